// Round 1
// baseline (27402.200 us; speedup 1.0000x reference)
//
#include <hip/hip_runtime.h>
#include <math.h>

// ---------------- problem constants ----------------
#define Bb   128
#define Hd   1024
#define Ld   256
#define Cd   20
#define Nd   30
#define Md   3

#define NWG  256     // one workgroup per CU
#define NTHR 512     // 8 waves

using bfrag = __attribute__((ext_vector_type(8)))  short;  // 8 bf16 (4 VGPRs)
using f32x4 = __attribute__((ext_vector_type(4)))  float;  // 16x16 C/D

union Pack8 { bfrag v; unsigned short u[8]; };

__device__ __forceinline__ float sigm(float x) { return 1.0f / (1.0f + expf(-x)); }

__device__ __forceinline__ unsigned short bf_rne(float x) {
    unsigned u = __float_as_uint(x);
    unsigned r = (u + 0x7fffu + ((u >> 16) & 1u)) >> 16;
    return (unsigned short)r;
}
__device__ __forceinline__ float bf_f(unsigned short h) {
    return __uint_as_float(((unsigned)h) << 16);
}

#define MFMA16(a,b,c) __builtin_amdgcn_mfma_f32_16x16x32_bf16((a),(b),(c),0,0,0)

// ---------------- device-wide barrier (agent scope, generation counter) ------
// bar[0] = arrive counter, bar[16] = generation (separate cache lines)
__device__ __forceinline__ void gridbar(unsigned* bar) {
    __syncthreads();                 // all WG stores drained to L2 (vmcnt(0))
    if (threadIdx.x == 0) {
        unsigned g = __hip_atomic_load(&bar[16], __ATOMIC_RELAXED, __HIP_MEMORY_SCOPE_AGENT);
        unsigned v = __hip_atomic_fetch_add(&bar[0], 1u, __ATOMIC_ACQ_REL, __HIP_MEMORY_SCOPE_AGENT);
        if (v == (unsigned)(NWG - 1)) {
            __hip_atomic_store(&bar[0], 0u, __ATOMIC_RELAXED, __HIP_MEMORY_SCOPE_AGENT);
            __hip_atomic_store(&bar[16], g + 1u, __ATOMIC_RELEASE, __HIP_MEMORY_SCOPE_AGENT);
        } else {
            while (__hip_atomic_load(&bar[16], __ATOMIC_RELAXED, __HIP_MEMORY_SCOPE_AGENT) == g)
                __builtin_amdgcn_s_sleep(2);
            __builtin_amdgcn_fence(__ATOMIC_ACQUIRE, "agent");
        }
    }
    __syncthreads();
}

__global__ void init_bar_kernel(unsigned* bar) {
    if (threadIdx.x < 32) bar[threadIdx.x] = 0u;
}

// ---------------- preamble kernels ----------------
__global__ void split_kernel(const float* __restrict__ src,
                             unsigned short* __restrict__ hi,
                             unsigned short* __restrict__ lo, int n)
{
    for (int i = blockIdx.x * blockDim.x + threadIdx.x; i < n; i += gridDim.x * blockDim.x) {
        float x = src[i];
        unsigned short h = bf_rne(x);
        hi[i] = h;
        lo[i] = bf_rne(x - bf_f(h));
    }
}

// pad Wfc [3][1024] f32 -> [16][1024] bf16 hi/lo (rows 3..15 zero)
__global__ void prep_wfc(const float* __restrict__ Wfc,
                         unsigned short* __restrict__ hi,
                         unsigned short* __restrict__ lo)
{
    int i = blockIdx.x * blockDim.x + threadIdx.x;
    if (i >= 16 * Hd) return;
    int r = i >> 10, k = i & 1023;
    float x = (r < Md) ? Wfc[r * Hd + k] : 0.0f;
    unsigned short h = bf_rne(x);
    hi[i] = h;
    lo[i] = bf_rne(x - bf_f(h));
}

// ---------------- persistent fused sequence kernel ----------------
// 256 WGs x 512 thr (one per CU). Each WG owns 4 j-columns of both cells:
// 16 gate-columns each for Whh1 / Wih2 / Whh2, LDS-resident in bf16
// (96 KB, XOR-swizzled k8-blocks for conflict-free ds_read_b128).
// Per step: phase1 = h1prev@Whh1 + h2prev@Whh2 (+FC on h2prev, +small seg),
// elementwise cell1 -> h1 hi/lo global; barrier; phase2 = h1@Wih2,
// elementwise cell2 -> h2 hi/lo global; barrier. c1/c2 live in VGPRs.
__global__ __launch_bounds__(NTHR, 2) void lstm_seq(
    const float* __restrict__ cond, const float* __restrict__ dmask,
    const float* __restrict__ Wih1f, const float* __restrict__ Whh1f,
    const float* __restrict__ bih1, const float* __restrict__ bhh1,
    const float* __restrict__ Wih2f, const float* __restrict__ Whh2f,
    const float* __restrict__ bih2, const float* __restrict__ bhh2,
    const float* __restrict__ bfcp,
    const float* __restrict__ c1f, const float* __restrict__ c2f,
    const unsigned short* __restrict__ wfch, const unsigned short* __restrict__ wfcl,
    unsigned short* __restrict__ h1h0, unsigned short* __restrict__ h1l0,
    unsigned short* __restrict__ h1h1, unsigned short* __restrict__ h1l1,
    unsigned short* __restrict__ h2h0, unsigned short* __restrict__ h2l0,
    unsigned short* __restrict__ h2h1, unsigned short* __restrict__ h2l1,
    float* __restrict__ outp, unsigned* bar)
{
    __shared__ unsigned short Wl1[16][1024];   // Whh1 slice
    __shared__ unsigned short Wl2[16][1024];   // Wih2 slice
    __shared__ unsigned short Wl3[16][1024];   // Whh2 slice
    __shared__ unsigned short Wsm[16][48];     // Wih1 slice (K=23 pad 32; 48 keeps rows 16B-aligned)
    __shared__ float gates[128][17];
    __shared__ float fcbuf[128][3];            // out[t-1] (redundant per-WG copy)
    __shared__ float biasS1[16], biasS2[16];

    const int tid  = threadIdx.x;
    const int wave = tid >> 6;
    const int lane = tid & 63;
    const int lm = lane & 15;          // A-row / B-col within tile
    const int lq = lane >> 4;          // k-chunk (8 bf16 each)
    const int eb = tid >> 2;           // elementwise batch row
    const int ejj = tid & 3;           // elementwise j within slice
    const int j0 = blockIdx.x * 4;

    // ---- one-time: weight slices -> LDS (bf16, k8-block XOR swizzle) ----
    for (int idx = tid; idx < 16 * 1024; idx += NTHR) {
        const int n = idx >> 10, k = idx & 1023;
        const size_t gr = (size_t)((n >> 2) * Hd + j0 + (n & 3)) * Hd + k;
        const int kp = (((k >> 3) ^ (n & 7)) << 3) | (k & 7);
        Wl1[n][kp] = bf_rne(Whh1f[gr]);
        Wl2[n][kp] = bf_rne(Wih2f[gr]);
        Wl3[n][kp] = bf_rne(Whh2f[gr]);
    }
    for (int idx = tid; idx < 16 * 48; idx += NTHR) {
        const int n = idx / 48, k = idx - n * 48;
        const int gr = (n >> 2) * Hd + j0 + (n & 3);
        Wsm[n][k] = (k < Cd + Md) ? bf_rne(Wih1f[(size_t)gr * (Cd + Md) + k]) : (unsigned short)0;
    }
    if (tid < 16) {
        const int gr = (tid >> 2) * Hd + j0 + (tid & 3);
        biasS1[tid] = bih1[gr] + bhh1[gr];
        biasS2[tid] = bih2[gr] + bhh2[gr];
    }

    const unsigned eoff = (unsigned)eb * Hd + (unsigned)(j0 + ejj);
    float c1 = c1f[eoff];
    float c2 = c2f[eoff];
    const float bfcv = (lm < Md) ? bfcp[lm] : 0.0f;
    __syncthreads();

    const unsigned aoff = (unsigned)(16 * wave + lm) * (Hd * 2) + (unsigned)lq * 16;  // byte off into h-matrices
    const char* w1p = (const char*)&Wl1[lm][0];
    const char* w2p = (const char*)&Wl2[lm][0];
    const char* w3p = (const char*)&Wl3[lm][0];
    const char* fhp = (const char*)wfch + aoff - (unsigned)(16 * wave) * (Hd * 2) + (unsigned)lm * 0; // see below
    // Wfc padded rows indexed by lm directly:
    const char* wfh = (const char*)wfch + (unsigned)lm * (Hd * 2) + (unsigned)lq * 16;
    const char* wfl = (const char*)wfcl + (unsigned)lm * (Hd * 2) + (unsigned)lq * 16;
    (void)fhp;

    for (int t = 1; t < Ld; ++t) {
        const int cur = t & 1;
        const unsigned short* Ah1 = cur ? h1h0 : h1h1;   // prev buffers
        const unsigned short* Al1 = cur ? h1l0 : h1l1;
        const unsigned short* Ah2 = cur ? h2h0 : h2h1;
        const unsigned short* Al2 = cur ? h2l0 : h2l1;
        unsigned short* O1h = cur ? h1h1 : h1h0;         // cur buffers
        unsigned short* O1l = cur ? h1l1 : h1l0;
        unsigned short* O2h = cur ? h2h1 : h2h0;
        unsigned short* O2l = cur ? h2l1 : h2l0;

        // prefetch dropout mask for this thread's (b, j)
        const float mymask = dmask[(size_t)t * (Bb * Hd) + eoff];

        // ---- phase 1: acc1 = h1prev@Whh1^T ; acc2 = h2prev@Whh2^T ; accF = h2prev@Wfc^T
        f32x4 acc1 = {0.f, 0.f, 0.f, 0.f};
        f32x4 acc2 = {0.f, 0.f, 0.f, 0.f};
        f32x4 accF = {0.f, 0.f, 0.f, 0.f};
        {
            const char* a1h = (const char*)Ah1 + aoff;
            const char* a1l = (const char*)Al1 + aoff;
            const char* a2h = (const char*)Ah2 + aoff;
            const char* a2l = (const char*)Al2 + aoff;
            #pragma unroll 4
            for (int ks = 0; ks < 32; ++ks) {
                const int ko = ks * 64;
                const bfrag x1h = *(const bfrag*)(a1h + ko);
                const bfrag x1l = *(const bfrag*)(a1l + ko);
                const bfrag x2h = *(const bfrag*)(a2h + ko);
                const bfrag x2l = *(const bfrag*)(a2l + ko);
                const bfrag wh  = *(const bfrag*)(wfh + ko);
                const bfrag wl  = *(const bfrag*)(wfl + ko);
                const int bo = (((ks * 4 + lq) ^ (lm & 7)) << 4);
                const bfrag b1 = *(const bfrag*)(w1p + bo);
                const bfrag b3 = *(const bfrag*)(w3p + bo);
                acc1 = MFMA16(x1h, b1, acc1);
                acc2 = MFMA16(x2h, b3, acc2);
                accF = MFMA16(x2h, wh, accF);
                acc1 = MFMA16(x1l, b1, acc1);
                acc2 = MFMA16(x2l, b3, acc2);
                accF = MFMA16(x2l, wh, accF);
                accF = MFMA16(x2h, wl, accF);
            }
        }
        // out[t-1] = accF + bfc ; every WG keeps a copy in LDS, WG0 writes d_out
        #pragma unroll
        for (int r = 0; r < 4; ++r) {
            if (lm < Md) {
                const int row = 16 * wave + lq * 4 + r;
                const float ov = accF[r] + bfcv;
                fcbuf[row][lm] = ov;
                if (blockIdx.x == 0)
                    outp[(size_t)(t - 1) * (Bb * Md) + row * Md + lm] = ov;
            }
        }
        __syncthreads();

        // small segment: cat(cond[t], out[t-1]) @ Wih1^T  (K=32 padded)
        {
            const int row = 16 * wave + lm;
            const float* crow = cond + ((size_t)t * Bb + row) * Cd;
            float xv[8];
            #pragma unroll
            for (int i = 0; i < 8; ++i) {
                const int k = lq * 8 + i;
                float x = 0.0f;
                if (k < Cd) x = crow[k];
                else if (k < Cd + Md) x = fcbuf[row][k - Cd];
                xv[i] = x;
            }
            Pack8 ah, al;
            #pragma unroll
            for (int i = 0; i < 8; ++i) {
                const unsigned short h = bf_rne(xv[i]);
                ah.u[i] = h;
                al.u[i] = bf_rne(xv[i] - bf_f(h));
            }
            const bfrag bs = *(const bfrag*)&Wsm[lm][lq * 8];
            acc1 = MFMA16(ah.v, bs, acc1);
            acc1 = MFMA16(al.v, bs, acc1);
        }

        // exchange + elementwise (cell1)
        #pragma unroll
        for (int r = 0; r < 4; ++r) gates[16 * wave + lq * 4 + r][lm] = acc1[r];
        __syncthreads();
        {
            const float gi = gates[eb][ejj]      + biasS1[ejj];
            const float gf = gates[eb][4 + ejj]  + biasS1[4 + ejj];
            const float gg = gates[eb][8 + ejj]  + biasS1[8 + ejj];
            const float go = gates[eb][12 + ejj] + biasS1[12 + ejj];
            const float cn = sigm(gf) * c1 + sigm(gi) * tanhf(gg);
            c1 = cn;
            const float hv = sigm(go) * tanhf(cn) * mymask;
            const unsigned short hh = bf_rne(hv);
            O1h[eoff] = hh;
            O1l[eoff] = bf_rne(hv - bf_f(hh));
        }
        gridbar(bar);

        // ---- phase 2: acc2 += h1cur@Wih2^T ; elementwise cell2 ----
        {
            const char* a1h = (const char*)O1h + aoff;
            const char* a1l = (const char*)O1l + aoff;
            #pragma unroll 4
            for (int ks = 0; ks < 32; ++ks) {
                const int ko = ks * 64;
                const bfrag xh = *(const bfrag*)(a1h + ko);
                const bfrag xl = *(const bfrag*)(a1l + ko);
                const int bo = (((ks * 4 + lq) ^ (lm & 7)) << 4);
                const bfrag b2 = *(const bfrag*)(w2p + bo);
                acc2 = MFMA16(xh, b2, acc2);
                acc2 = MFMA16(xl, b2, acc2);
            }
        }
        #pragma unroll
        for (int r = 0; r < 4; ++r) gates[16 * wave + lq * 4 + r][lm] = acc2[r];
        __syncthreads();
        {
            const float gi = gates[eb][ejj]      + biasS2[ejj];
            const float gf = gates[eb][4 + ejj]  + biasS2[4 + ejj];
            const float gg = gates[eb][8 + ejj]  + biasS2[8 + ejj];
            const float go = gates[eb][12 + ejj] + biasS2[12 + ejj];
            const float cn = sigm(gf) * c2 + sigm(gi) * tanhf(gg);
            c2 = cn;
            const float hv = sigm(go) * tanhf(cn);
            const unsigned short hh = bf_rne(hv);
            O2h[eoff] = hh;
            O2l[eoff] = bf_rne(hv - bf_f(hh));
        }
        gridbar(bar);
    }

    // ---- epilogue: out[255] = h2[255]@Wfc^T + bfc (WG0 only) ----
    if (blockIdx.x == 0) {
        const unsigned short* Eh = ((Ld - 1) & 1) ? h2h1 : h2h0;
        const unsigned short* El = ((Ld - 1) & 1) ? h2l1 : h2l0;
        f32x4 accF = {0.f, 0.f, 0.f, 0.f};
        const char* a2h = (const char*)Eh + aoff;
        const char* a2l = (const char*)El + aoff;
        #pragma unroll 4
        for (int ks = 0; ks < 32; ++ks) {
            const int ko = ks * 64;
            const bfrag xh = *(const bfrag*)(a2h + ko);
            const bfrag xl = *(const bfrag*)(a2l + ko);
            const bfrag wh = *(const bfrag*)(wfh + ko);
            const bfrag wl = *(const bfrag*)(wfl + ko);
            accF = MFMA16(xh, wh, accF);
            accF = MFMA16(xl, wh, accF);
            accF = MFMA16(xh, wl, accF);
        }
        #pragma unroll
        for (int r = 0; r < 4; ++r) {
            if (lm < Md) {
                const int row = 16 * wave + lq * 4 + r;
                outp[(size_t)(Ld - 1) * (Bb * Md) + row * Md + lm] = accF[r] + bfcv;
            }
        }
    }
}

// ---------------- R0 fp32 VALU cell kernel (step 0 + ws fallback) ----------------
#define BT   64
#define JT   8
#define RT   32
#define KC   64
#define NT   256
#define NCHUNK 16
#define XSs  68
#define SMs  52
#define GBs  33

__global__ __launch_bounds__(NT) void lstm_cell_kernel(
    const float* __restrict__ Xbig0, const float* __restrict__ Wbig0,
    const float* __restrict__ Xbig1, const float* __restrict__ Wbig1,
    const float* __restrict__ Xsm0p, int K0,
    const float* __restrict__ Xsm1p, int K1,
    const float* __restrict__ Wsmall,
    const float* __restrict__ bih, const float* __restrict__ bhh,
    const float* __restrict__ cprev, float* __restrict__ cnew,
    const float* __restrict__ mask,
    float* __restrict__ hnew,
    const float* __restrict__ Wfc, const float* __restrict__ bfc,
    float* __restrict__ outp, int initOut)
{
    __shared__ float Xs[BT][XSs];
    __shared__ float Ws[RT][XSs];
    __shared__ float gbuf[BT][GBs];
    __shared__ float hbuf[BT][JT];
    __shared__ float Xsm[BT][SMs];
    __shared__ float Wsm[RT][SMs];

    const int tid = threadIdx.x;
    const int j0  = blockIdx.x * JT;
    const int b0  = blockIdx.y * BT;
    const int jp  = tid & 15;
    const int bq  = tid >> 4;

    auto GROW = [&](int r) { return ((r >> 3) * Hd + j0 + (r & 7)); };

    float acc[4][2];
    #pragma unroll
    for (int i = 0; i < 4; ++i) { acc[i][0] = 0.f; acc[i][1] = 0.f; }

    if (initOut && blockIdx.x == 0 && blockIdx.y == 0) {
        for (int i = tid; i < Bb * 3; i += NT) outp[i] = bfc[i % 3];
    }

    for (int seg = 0; seg < 2; ++seg) {
        const float* __restrict__ Xg = (seg == 0) ? Xbig0 : Xbig1;
        const float* __restrict__ Wg = (seg == 0) ? Wbig0 : Wbig1;
        if (Xg == nullptr) continue;

        float4 xr[4], wr[2];
        #pragma unroll
        for (int p = 0; p < 4; ++p) {
            int fi = p * NT + tid; int bloc = fi >> 4; int kq = fi & 15;
            xr[p] = *(const float4*)(Xg + (size_t)(b0 + bloc) * Hd + kq * 4);
        }
        #pragma unroll
        for (int p = 0; p < 2; ++p) {
            int fi = p * NT + tid; int r = fi >> 4; int kq = fi & 15;
            wr[p] = *(const float4*)(Wg + (size_t)GROW(r) * Hd + kq * 4);
        }
        #pragma unroll
        for (int p = 0; p < 4; ++p) { int fi = p * NT + tid; *(float4*)&Xs[fi >> 4][(fi & 15) * 4] = xr[p]; }
        #pragma unroll
        for (int p = 0; p < 2; ++p) { int fi = p * NT + tid; *(float4*)&Ws[fi >> 4][(fi & 15) * 4] = wr[p]; }
        __syncthreads();

        for (int kc = 0; kc < NCHUNK; ++kc) {
            const bool more = (kc + 1) < NCHUNK;
            if (more) {
                const int k0n = (kc + 1) * KC;
                #pragma unroll
                for (int p = 0; p < 4; ++p) {
                    int fi = p * NT + tid; int bloc = fi >> 4; int kq = fi & 15;
                    xr[p] = *(const float4*)(Xg + (size_t)(b0 + bloc) * Hd + k0n + kq * 4);
                }
                #pragma unroll
                for (int p = 0; p < 2; ++p) {
                    int fi = p * NT + tid; int r = fi >> 4; int kq = fi & 15;
                    wr[p] = *(const float4*)(Wg + (size_t)GROW(r) * Hd + k0n + kq * 4);
                }
            }
            #pragma unroll 4
            for (int kk = 0; kk < KC; kk += 4) {
                float4 w0 = *(const float4*)&Ws[jp][kk];
                float4 w1 = *(const float4*)&Ws[jp + 16][kk];
                #pragma unroll
                for (int bb = 0; bb < 4; ++bb) {
                    float4 xvv = *(const float4*)&Xs[bq + 16 * bb][kk];
                    acc[bb][0] += xvv.x * w0.x + xvv.y * w0.y + xvv.z * w0.z + xvv.w * w0.w;
                    acc[bb][1] += xvv.x * w1.x + xvv.y * w1.y + xvv.z * w1.z + xvv.w * w1.w;
                }
            }
            __syncthreads();
            if (more) {
                #pragma unroll
                for (int p = 0; p < 4; ++p) { int fi = p * NT + tid; *(float4*)&Xs[fi >> 4][(fi & 15) * 4] = xr[p]; }
                #pragma unroll
                for (int p = 0; p < 2; ++p) { int fi = p * NT + tid; *(float4*)&Ws[fi >> 4][(fi & 15) * 4] = wr[p]; }
                __syncthreads();
            }
        }
    }

    if (Wsmall) {
        const int Kt = K0 + K1;
        for (int i = tid; i < BT * Kt; i += NT) {
            int bloc = i / Kt, k = i % Kt;
            Xsm[bloc][k] = (k < K0) ? Xsm0p[(size_t)(b0 + bloc) * K0 + k]
                                    : Xsm1p[(size_t)(b0 + bloc) * K1 + (k - K0)];
        }
        for (int i = tid; i < RT * Kt; i += NT) {
            int r = i / Kt, k = i % Kt;
            Wsm[r][k] = Wsmall[(size_t)GROW(r) * Kt + k];
        }
        __syncthreads();
        for (int k = 0; k < Kt; ++k) {
            float w0 = Wsm[jp][k], w1 = Wsm[jp + 16][k];
            #pragma unroll
            for (int bb = 0; bb < 4; ++bb) {
                float xvv = Xsm[bq + 16 * bb][k];
                acc[bb][0] += xvv * w0;
                acc[bb][1] += xvv * w1;
            }
        }
    }

    __syncthreads();
    #pragma unroll
    for (int bb = 0; bb < 4; ++bb) {
        gbuf[bq + 16 * bb][jp]      = acc[bb][0];
        gbuf[bq + 16 * bb][jp + 16] = acc[bb][1];
    }
    __syncthreads();

    for (int p = tid; p < BT * JT; p += NT) {
        int bloc = p & (BT - 1);
        int j    = p >> 6;
        int bg   = b0 + bloc;
        int jc   = j0 + j;
        float gi = gbuf[bloc][j]      + bih[jc]          + bhh[jc];
        float gf = gbuf[bloc][8 + j]  + bih[Hd + jc]     + bhh[Hd + jc];
        float gg = gbuf[bloc][16 + j] + bih[2 * Hd + jc] + bhh[2 * Hd + jc];
        float go = gbuf[bloc][24 + j] + bih[3 * Hd + jc] + bhh[3 * Hd + jc];
        float cp = cprev[(size_t)bg * Hd + jc];
        float cn = sigm(gf) * cp + sigm(gi) * tanhf(gg);
        float hv = sigm(go) * tanhf(cn);
        if (mask) hv *= mask[(size_t)bg * Hd + jc];
        cnew[(size_t)bg * Hd + jc] = cn;
        hnew[(size_t)bg * Hd + jc] = hv;
        hbuf[bloc][j] = hv;
    }

    if (Wfc) {
        __syncthreads();
        if (tid < BT) {
            int bg = b0 + tid;
            #pragma unroll
            for (int m = 0; m < 3; ++m) {
                float s = 0.f;
                #pragma unroll
                for (int j = 0; j < JT; ++j) s += hbuf[tid][j] * Wfc[m * Hd + j0 + j];
                atomicAdd(&outp[bg * 3 + m], s);
            }
        }
    }
}

// ---------------- launch ----------------
extern "C" void kernel_launch(void* const* d_in, const int* in_sizes, int n_in,
                              void* d_out, int out_size, void* d_ws, size_t ws_size,
                              hipStream_t stream)
{
    (void)in_sizes; (void)n_in; (void)out_size;
    const float* cond   = (const float*)d_in[0];
    const float* noise  = (const float*)d_in[1];
    const float* h_init = (const float*)d_in[2];
    const float* c_init = (const float*)d_in[3];
    const float* dmask  = (const float*)d_in[4];
    const float* Wih0   = (const float*)d_in[5];
    const float* Whh0   = (const float*)d_in[6];
    const float* bih0   = (const float*)d_in[7];
    const float* bhh0   = (const float*)d_in[8];
    const float* Wih1   = (const float*)d_in[9];
    const float* Whh1   = (const float*)d_in[10];
    const float* bih1   = (const float*)d_in[11];
    const float* bhh1   = (const float*)d_in[12];
    const float* Wih2   = (const float*)d_in[13];
    const float* Whh2   = (const float*)d_in[14];
    const float* bih2   = (const float*)d_in[15];
    const float* bhh2   = (const float*)d_in[16];
    const float* Wfc    = (const float*)d_in[17];
    const float* bfc    = (const float*)d_in[18];
    float* out = (float*)d_out;

    char* wsb = (char*)d_ws;
    size_t off = 0;
    auto alloc = [&](size_t bytes) { size_t o = off; off += (bytes + 255) & ~(size_t)255; return o; };

    const size_t HB = (size_t)Bb * Hd * 2;   // bf16 h buffer
    const size_t HF = (size_t)Bb * Hd * 4;   // fp32

    size_t o_h1h[2] = { alloc(HB), alloc(HB) };
    size_t o_h1l[2] = { alloc(HB), alloc(HB) };
    size_t o_h2h[2] = { alloc(HB), alloc(HB) };
    size_t o_h2l[2] = { alloc(HB), alloc(HB) };
    size_t o_c1 = alloc(HF), o_c2 = alloc(HF);
    size_t o_f1 = alloc(HF), o_f2 = alloc(HF);
    size_t o_wfh = alloc((size_t)16 * Hd * 2);
    size_t o_wfl = alloc((size_t)16 * Hd * 2);
    size_t o_bar = alloc(256);
    const size_t needed = off;

    if (ws_size < needed) {
        // -------- fallback: full R0 fp32 path --------
        float* ws = (float*)d_ws;
        const size_t S = (size_t)Bb * Hd;
        float* h1a = ws;         float* h1b = ws + S;
        float* h2a = ws + 2 * S; float* h2b = ws + 3 * S;
        float* c1  = ws + 4 * S; float* c2  = ws + 5 * S;
        dim3 grid(Hd / JT, Bb / BT);
        dim3 blk(NT);
        lstm_cell_kernel<<<grid, blk, 0, stream>>>(
            h_init, Whh0, nullptr, nullptr, cond, Cd, noise, Nd, Wih0,
            bih0, bhh0, c_init, c1, dmask, h1a, nullptr, bfc, out, 1);
        lstm_cell_kernel<<<grid, blk, 0, stream>>>(
            h1a, Wih2, h_init, Whh2, nullptr, 0, nullptr, 0, nullptr,
            bih2, bhh2, c_init, c2, nullptr, h2a, Wfc, bfc, out, 0);
        const float* h1prev = h1a; const float* h2prev = h2a;
        for (int t = 1; t < Ld; ++t) {
            float* h1cur = (t & 1) ? h1b : h1a;
            float* h2cur = (t & 1) ? h2b : h2a;
            lstm_cell_kernel<<<grid, blk, 0, stream>>>(
                h1prev, Whh1, nullptr, nullptr,
                cond + (size_t)t * Bb * Cd, Cd, out + (size_t)(t - 1) * Bb * Md, Md, Wih1,
                bih1, bhh1, c1, c1, dmask + (size_t)t * Bb * Hd, h1cur,
                nullptr, bfc, out + (size_t)t * Bb * Md, 1);
            lstm_cell_kernel<<<grid, blk, 0, stream>>>(
                h1cur, Wih2, h2prev, Whh2, nullptr, 0, nullptr, 0, nullptr,
                bih2, bhh2, c2, c2, nullptr, h2cur, Wfc, bfc, out + (size_t)t * Bb * Md, 0);
            h1prev = h1cur; h2prev = h2cur;
        }
        return;
    }

    auto U16 = [&](size_t o) { return (unsigned short*)(wsb + o); };
    auto F32 = [&](size_t o) { return (float*)(wsb + o); };
    unsigned* bar = (unsigned*)(wsb + o_bar);

    // preamble: barrier init + padded bf16 Wfc
    init_bar_kernel<<<1, 64, 0, stream>>>(bar);
    prep_wfc<<<64, 256, 0, stream>>>(Wfc, U16(o_wfh), U16(o_wfl));

    // step 0 via the proven fp32 kernel (writes out[0], c1, c2, h1, h2)
    {
        dim3 grid(Hd / JT, Bb / BT);
        dim3 blk(NT);
        lstm_cell_kernel<<<grid, blk, 0, stream>>>(
            h_init, Whh0, nullptr, nullptr, cond, Cd, noise, Nd, Wih0,
            bih0, bhh0, c_init, F32(o_c1), dmask, F32(o_f1), nullptr, bfc, out, 1);
        lstm_cell_kernel<<<grid, blk, 0, stream>>>(
            F32(o_f1), Wih2, h_init, Whh2, nullptr, 0, nullptr, 0, nullptr,
            bih2, bhh2, c_init, F32(o_c2), nullptr, F32(o_f2), Wfc, bfc, out, 0);
        split_kernel<<<256, 256, 0, stream>>>(F32(o_f1), U16(o_h1h[0]), U16(o_h1l[0]), Bb * Hd);
        split_kernel<<<256, 256, 0, stream>>>(F32(o_f2), U16(o_h2h[0]), U16(o_h2l[0]), Bb * Hd);
    }

    // steps 1..255 in one persistent kernel
    lstm_seq<<<NWG, NTHR, 0, stream>>>(
        cond, dmask, Wih1, Whh1, bih1, bhh1, Wih2, Whh2, bih2, bhh2,
        bfc, F32(o_c1), F32(o_c2), U16(o_wfh), U16(o_wfl),
        U16(o_h1h[0]), U16(o_h1l[0]), U16(o_h1h[1]), U16(o_h1l[1]),
        U16(o_h2h[0]), U16(o_h2l[0]), U16(o_h2h[1]), U16(o_h2l[1]),
        out, bar);
}

// Round 2
// 9234.302 us; speedup vs baseline: 2.9674x; 2.9674x over previous
//
#include <hip/hip_runtime.h>
#include <math.h>

// ---------------- problem constants ----------------
#define Bb   128
#define Hd   1024
#define Ld   256
#define Cd   20
#define Nd   30
#define Md   3

#define NWG  256     // one workgroup per CU
#define NTHR 512     // 8 waves

// barrier region word offsets (unsigned words, 64B-strided slots)
#define CW    16
#define XCNT0 0            // 8 slots
#define CCNT  (8*CW)
#define CGEN  (9*CW)
#define XARR1 (10*CW)      // 8 slots
#define GC1   (18*CW)
#define GEN1  (19*CW)
#define XD1   (20*CW)      // 8 slots
#define XARR2 (28*CW)
#define GC2   (36*CW)
#define GEN2  (37*CW)
#define XD2   (38*CW)      // 8 slots
#define BARWORDS 1024

using bfrag = __attribute__((ext_vector_type(8)))  short;  // 8 bf16
using f32x4 = __attribute__((ext_vector_type(4)))  float;  // 16x16 C/D

union Pack8 { bfrag v; unsigned short u[8]; };

__device__ __forceinline__ float sigm(float x) { return 1.0f / (1.0f + expf(-x)); }

__device__ __forceinline__ unsigned short bf_rne(float x) {
    unsigned u = __float_as_uint(x);
    unsigned r = (u + 0x7fffu + ((u >> 16) & 1u)) >> 16;
    return (unsigned short)r;
}
__device__ __forceinline__ float bf_f(unsigned short h) {
    return __uint_as_float(((unsigned)h) << 16);
}

#define MFMA16(a,b,c) __builtin_amdgcn_mfma_f32_16x16x32_bf16((a),(b),(c),0,0,0)

__global__ void init_bar_kernel(unsigned* bar) {
    int i = blockIdx.x * blockDim.x + threadIdx.x;
    if (i < BARWORDS) bar[i] = 0u;
}

// fp32 h -> bf16 hi/lo in k-grouped layout [k/8][b][8]
__global__ void split_kg(const float* __restrict__ src,
                         unsigned short* __restrict__ hi,
                         unsigned short* __restrict__ lo)
{
    int i = blockIdx.x * blockDim.x + threadIdx.x;
    if (i >= Bb * Hd) return;
    int b = i >> 10, k = i & 1023;
    float x = src[i];
    unsigned short h = bf_rne(x);
    int d = ((k >> 3) * Bb + b) * 8 + (k & 7);
    hi[d] = h;
    lo[d] = bf_rne(x - bf_f(h));
}

// pad Wfc [3][1024] f32 -> [16][1024] bf16 hi/lo (rows 3..15 zero)
__global__ void prep_wfc(const float* __restrict__ Wfc,
                         unsigned short* __restrict__ hi,
                         unsigned short* __restrict__ lo)
{
    int i = blockIdx.x * blockDim.x + threadIdx.x;
    if (i >= 16 * Hd) return;
    int r = i >> 10, k = i & 1023;
    float x = (r < Md) ? Wfc[r * Hd + k] : 0.0f;
    unsigned short h = bf_rne(x);
    hi[i] = h;
    lo[i] = bf_rne(x - bf_f(h));
}

// ---------------- persistent fused sequence kernel ----------------
// 256 WGs x 512 thr (one per CU). Each WG owns 4 j-columns of both cells;
// Whh1/Wih2/Whh2 slices LDS-resident (96 KB). c1/c2 in registers.
// Hierarchical grid barrier: 1 wbl2 + 1 L2-inv per XCD per barrier; all
// other WGs only vL1-inv. Both barriers' latency hidden under GEMMs.
__global__ __launch_bounds__(NTHR, 1) void lstm_seq(
    const float* __restrict__ cond, const float* __restrict__ dmask,
    const float* __restrict__ Wih1f, const float* __restrict__ Whh1f,
    const float* __restrict__ bih1, const float* __restrict__ bhh1,
    const float* __restrict__ Wih2f, const float* __restrict__ Whh2f,
    const float* __restrict__ bih2, const float* __restrict__ bhh2,
    const float* __restrict__ bfcp,
    const float* __restrict__ c1f, const float* __restrict__ c2f,
    const unsigned short* __restrict__ wfch, const unsigned short* __restrict__ wfcl,
    unsigned short* __restrict__ h1h0, unsigned short* __restrict__ h1l0,
    unsigned short* __restrict__ h1h1, unsigned short* __restrict__ h1l1,
    unsigned short* __restrict__ h2h0, unsigned short* __restrict__ h2l0,
    unsigned short* __restrict__ h2h1, unsigned short* __restrict__ h2l1,
    float* __restrict__ outp, unsigned* bar)
{
    __shared__ unsigned short Wl1[16][1024];   // Whh1 slice
    __shared__ unsigned short Wl2[16][1024];   // Wih2 slice
    __shared__ unsigned short Wl3[16][1024];   // Whh2 slice
    __shared__ unsigned short Wsm[16][48];     // Wih1 slice (K=23 pad, 16B-aligned rows)
    __shared__ float gates[128][17];
    __shared__ float fcbuf[128][3];            // out[t-1] (redundant per-WG copy)
    __shared__ float biasS1[16], biasS2[16];

    const int tid  = threadIdx.x;
    const int wave = tid >> 6;
    const int lane = tid & 63;
    const int lm = lane & 15;          // A-row (b) / B-col (n) within tile
    const int lq = lane >> 4;          // k-chunk (8 bf16)
    const int eb = tid >> 2;           // elementwise batch row
    const int ejj = tid & 3;           // elementwise j within slice
    const int bid = blockIdx.x;
    // adjacent j-slices on same (presumed) XCD -> line-exclusive h writes
    const int slice = (bid >> 3) + ((bid & 7) << 5);
    const int j0 = slice * 4;

    unsigned xreg;
    asm volatile("s_getreg_b32 %0, hwreg(HW_REG_XCC_ID)" : "=s"(xreg));
    const int xcd = (int)(xreg & 7u);

    // ---- one-time: weight slices -> LDS (bf16, k8-block XOR swizzle) ----
    for (int idx = tid; idx < 16 * 1024; idx += NTHR) {
        const int n = idx >> 10, k = idx & 1023;
        const size_t gr = (size_t)((n >> 2) * Hd + j0 + (n & 3)) * Hd + k;
        const int kp = (((k >> 3) ^ (n & 7)) << 3) | (k & 7);
        Wl1[n][kp] = bf_rne(Whh1f[gr]);
        Wl2[n][kp] = bf_rne(Wih2f[gr]);
        Wl3[n][kp] = bf_rne(Whh2f[gr]);
    }
    for (int idx = tid; idx < 16 * 48; idx += NTHR) {
        const int n = idx / 48, k = idx - n * 48;
        const int gr = (n >> 2) * Hd + j0 + (n & 3);
        Wsm[n][k] = (k < Cd + Md) ? bf_rne(Wih1f[(size_t)gr * (Cd + Md) + k]) : (unsigned short)0;
    }
    if (tid < 16) {
        const int gr = (tid >> 2) * Hd + j0 + (tid & 3);
        biasS1[tid] = bih1[gr] + bhh1[gr];
        biasS2[tid] = bih2[gr] + bhh2[gr];
    }

    // ---- census: expected WGs per XCD (once, heavy barrier OK) ----
    unsigned expX = 0, nx = 0;
    if (tid == 0) {
        __hip_atomic_fetch_add(&bar[XCNT0 + xcd * CW], 1u, __ATOMIC_RELAXED, __HIP_MEMORY_SCOPE_AGENT);
        unsigned v = __hip_atomic_fetch_add(&bar[CCNT], 1u, __ATOMIC_ACQ_REL, __HIP_MEMORY_SCOPE_AGENT);
        if (v == (unsigned)(NWG - 1)) {
            __hip_atomic_store(&bar[CGEN], 1u, __ATOMIC_RELEASE, __HIP_MEMORY_SCOPE_AGENT);
        } else {
            while (__hip_atomic_load(&bar[CGEN], __ATOMIC_RELAXED, __HIP_MEMORY_SCOPE_AGENT) == 0u)
                __builtin_amdgcn_s_sleep(8);
            __builtin_amdgcn_fence(__ATOMIC_ACQUIRE, "agent");
        }
        expX = __hip_atomic_load(&bar[XCNT0 + xcd * CW], __ATOMIC_RELAXED, __HIP_MEMORY_SCOPE_AGENT);
        for (int x = 0; x < 8; ++x)
            nx += (__hip_atomic_load(&bar[XCNT0 + x * CW], __ATOMIC_RELAXED, __HIP_MEMORY_SCOPE_AGENT) != 0u) ? 1u : 0u;
    }
    __syncthreads();   // also publishes LDS weight fill

    // ---- per-thread constants ----
    const unsigned eoffLin = (unsigned)eb * Hd + (unsigned)(j0 + ejj);
    const int jw = j0 + ejj;
    const unsigned idxKG = (unsigned)((jw >> 3) * Bb + eb) * 8u + (unsigned)(jw & 7);
    float c1 = c1f[eoffLin];
    float c2 = c2f[eoffLin];
    const float bfcv = (lm < Md) ? bfcp[lm] : 0.0f;
    const unsigned aoffB = (unsigned)(16 * wave + lm) * 16u + (unsigned)lq * 2048u;
    const char* w1p = (const char*)&Wl1[lm][0];
    const char* w2p = (const char*)&Wl2[lm][0];
    const char* w3p = (const char*)&Wl3[lm][0];
    const char* wfh = (const char*)wfch + (unsigned)lm * 2048u + (unsigned)lq * 16u;
    const char* wfl = (const char*)wfcl + (unsigned)lm * 2048u + (unsigned)lq * 16u;
    const bfrag zfrag = {0,0,0,0,0,0,0,0};
    const f32x4 z4 = {0.f, 0.f, 0.f, 0.f};

    // ---- barrier ops ----
    auto b_arrive = [&](unsigned* XA, unsigned* GC, unsigned* GEN, unsigned t) -> bool {
        __syncthreads();                 // drains all waves' stores to L2
        bool am = false;
        if (tid == 0) {
            unsigned v = __hip_atomic_fetch_add(&XA[xcd * CW], 1u, __ATOMIC_RELAXED, __HIP_MEMORY_SCOPE_AGENT);
            if (v + 1u == expX * t) {    // last WG on this XCD for step t
                am = true;
                __builtin_amdgcn_fence(__ATOMIC_RELEASE, "agent");   // 1 wbl2/XCD
                unsigned w = __hip_atomic_fetch_add(GC, 1u, __ATOMIC_RELAXED, __HIP_MEMORY_SCOPE_AGENT);
                if (w + 1u == nx * t)
                    __hip_atomic_store(GEN, t, __ATOMIC_RELEASE, __HIP_MEMORY_SCOPE_AGENT);
            }
        }
        return am;
    };
    auto b_wait = [&](unsigned* GEN, unsigned* XD, unsigned t, bool am) {
        if (tid == 0) {
            while (__hip_atomic_load(GEN, __ATOMIC_RELAXED, __HIP_MEMORY_SCOPE_AGENT) < t)
                __builtin_amdgcn_s_sleep(2);
            if (am) {
                __builtin_amdgcn_fence(__ATOMIC_ACQUIRE, "agent");   // 1 L2-inv/XCD
                __hip_atomic_store(&XD[xcd * CW], t, __ATOMIC_RELAXED, __HIP_MEMORY_SCOPE_AGENT);
            } else {
                while (__hip_atomic_load(&XD[xcd * CW], __ATOMIC_RELAXED, __HIP_MEMORY_SCOPE_AGENT) < t)
                    __builtin_amdgcn_s_sleep(2);
            }
        }
        __syncthreads();
        asm volatile("buffer_inv sc0\n\ts_waitcnt vmcnt(0)" ::: "memory");  // per-CU vL1 inv
    };

    // ---- GEMM helpers (A from global kg-layout, B from LDS swizzled) ----
    auto gemmA = [&](const unsigned short* Hh, const unsigned short* Hl,
                     const char* wp, f32x4 acc) -> f32x4 {
        const char* ah = (const char*)Hh + aoffB;
        const char* al = (const char*)Hl + aoffB;
        #pragma unroll 4
        for (int ks = 0; ks < 32; ++ks) {
            bfrag xh = *(const bfrag*)(ah + ks * 8192);
            bfrag xl = *(const bfrag*)(al + ks * 8192);
            bfrag b  = *(const bfrag*)(wp + ((((ks * 4 + lq) ^ (lm & 7)) << 4)));
            acc = MFMA16(xh, b, acc);
            acc = MFMA16(xl, b, acc);
        }
        return acc;
    };
    auto gemmFC = [&](const unsigned short* Hh, const unsigned short* Hl) -> f32x4 {
        f32x4 aF = z4;
        const char* ah = (const char*)Hh + aoffB;
        const char* al = (const char*)Hl + aoffB;
        const bool fcl = (lm < Md);
        #pragma unroll 4
        for (int ks = 0; ks < 32; ++ks) {
            bfrag xh = *(const bfrag*)(ah + ks * 8192);
            bfrag xl = *(const bfrag*)(al + ks * 8192);
            bfrag wh = zfrag, wl = zfrag;
            if (fcl) { wh = *(const bfrag*)(wfh + ks * 64); wl = *(const bfrag*)(wfl + ks * 64); }
            aF = MFMA16(xh, wh, aF);
            aF = MFMA16(xl, wh, aF);
            aF = MFMA16(xh, wl, aF);
        }
        return aF;
    };
    auto putGates = [&](const f32x4& a) {
        #pragma unroll
        for (int r = 0; r < 4; ++r) gates[16 * wave + lq * 4 + r][lm] = a[r];
    };
    auto putFC = [&](const f32x4& aF, int tOut) {
        #pragma unroll
        for (int r = 0; r < 4; ++r) {
            if (lm < Md) {
                const int row = 16 * wave + lq * 4 + r;
                const float ov = aF[r] + bfcv;
                fcbuf[row][lm] = ov;
                if (bid == 0) outp[(size_t)tOut * (Bb * Md) + row * Md + lm] = ov;
            }
        }
    };
    auto cellEW = [&](const float* biasS, float& c, float maskv,
                      unsigned short* Oh, unsigned short* Ol) {
        const float gi = gates[eb][ejj]      + biasS[ejj];
        const float gf = gates[eb][4 + ejj]  + biasS[4 + ejj];
        const float gg = gates[eb][8 + ejj]  + biasS[8 + ejj];
        const float go = gates[eb][12 + ejj] + biasS[12 + ejj];
        const float cn = sigm(gf) * c + sigm(gi) * tanhf(gg);
        c = cn;
        float hv = sigm(go) * tanhf(cn) * maskv;
        const unsigned short hh = bf_rne(hv);
        Oh[idxKG] = hh;
        Ol[idxKG] = bf_rne(hv - bf_f(hh));
    };
    float cpre[8];
    auto prefetchCond = [&](int tn, float* cp) {
        const int row = 16 * wave + lm;
        const float* crow = cond + ((size_t)tn * Bb + row) * Cd;
        #pragma unroll
        for (int i = 0; i < 8; ++i) { int k = lq * 8 + i; cp[i] = (k < Cd) ? crow[k] : 0.f; }
    };
    auto smallSeg = [&](f32x4& a1) {
        const int row = 16 * wave + lm;
        Pack8 ah, al;
        #pragma unroll
        for (int i = 0; i < 8; ++i) {
            const int k = lq * 8 + i;
            float x = (k < Cd) ? cpre[i] : ((k < Cd + Md) ? fcbuf[row][k - Cd] : 0.f);
            const unsigned short h = bf_rne(x);
            ah.u[i] = h;
            al.u[i] = bf_rne(x - bf_f(h));
        }
        const bfrag bs = *(const bfrag*)&Wsm[lm][lq * 8];
        a1 = MFMA16(ah.v, bs, a1);
        a1 = MFMA16(al.v, bs, a1);
    };

    // ---- prologue: prefetch t=1 inputs, acc1 = h1[0]@Whh1 ----
    prefetchCond(1, cpre);
    float mymask = dmask[(size_t)(Bb * Hd) + eoffLin];
    f32x4 acc1 = gemmA(h1h0, h1l0, w1p, z4);
    bool last2 = false;

    unsigned* XA1 = bar + XARR1; unsigned* G1 = bar + GC1; unsigned* E1 = bar + GEN1; unsigned* D1 = bar + XD1;
    unsigned* XA2 = bar + XARR2; unsigned* G2 = bar + GC2; unsigned* E2 = bar + GEN2; unsigned* D2 = bar + XD2;

    for (int t = 1; t < Ld; ++t) {
        const int cur = t & 1;
        const unsigned short* A2h = cur ? h2h0 : h2h1;   // h2 prev
        const unsigned short* A2l = cur ? h2l0 : h2l1;
        unsigned short* O1h = cur ? h1h1 : h1h0;         // h1 cur
        unsigned short* O1l = cur ? h1l1 : h1l0;
        unsigned short* O2h = cur ? h2h1 : h2h0;         // h2 cur
        unsigned short* O2l = cur ? h2l1 : h2l0;

        // h2prev visible (t=1: trivially passes, cross-kernel coherence)
        b_wait(E2, D2, (unsigned)(t - 1), last2);

        // FC: out[t-1] = h2prev @ Wfc^T + bfc (every WG; WG0 writes d_out)
        f32x4 accF = gemmFC(A2h, A2l);
        putFC(accF, t - 1);
        __syncthreads();

        // cell1: acc1 (precomputed) + small segment -> gates -> elementwise
        smallSeg(acc1);
        putGates(acc1);
        __syncthreads();
        cellEW(biasS1, c1, mymask, O1h, O1l);

        const bool last1 = b_arrive(XA1, G1, E1, (unsigned)t);
        // overlap bar1 latency: acc2 = h2prev @ Whh2 (L2-warm re-read)
        f32x4 acc2 = gemmA(A2h, A2l, w3p, z4);
        b_wait(E1, D1, (unsigned)t, last1);

        // cell2: acc2 += h1cur @ Wih2 -> gates -> elementwise
        acc2 = gemmA(O1h, O1l, w2p, acc2);
        putGates(acc2);
        __syncthreads();
        cellEW(biasS2, c2, 1.0f, O2h, O2l);

        last2 = b_arrive(XA2, G2, E2, (unsigned)t);
        // overlap bar2 latency: next step's big GEMM + input prefetch
        if (t < Ld - 1) {
            prefetchCond(t + 1, cpre);
            mymask = dmask[(size_t)(t + 1) * (Bb * Hd) + eoffLin];
            acc1 = gemmA(O1h, O1l, w1p, z4);             // h1cur @ Whh1
        }
    }

    // ---- epilogue: out[255] = h2[255]@Wfc^T + bfc (WG0 only) ----
    if (bid == 0) {
        if (tid == 0) {
            while (__hip_atomic_load(E2, __ATOMIC_RELAXED, __HIP_MEMORY_SCOPE_AGENT) < (unsigned)(Ld - 1))
                __builtin_amdgcn_s_sleep(2);
            __builtin_amdgcn_fence(__ATOMIC_ACQUIRE, "agent");
        }
        __syncthreads();
        asm volatile("buffer_inv sc0\n\ts_waitcnt vmcnt(0)" ::: "memory");
        const unsigned short* Eh = ((Ld - 1) & 1) ? h2h1 : h2h0;
        const unsigned short* El = ((Ld - 1) & 1) ? h2l1 : h2l0;
        f32x4 aF = gemmFC(Eh, El);
        #pragma unroll
        for (int r = 0; r < 4; ++r) {
            if (lm < Md) {
                const int row = 16 * wave + lq * 4 + r;
                outp[(size_t)(Ld - 1) * (Bb * Md) + row * Md + lm] = aF[r] + bfcv;
            }
        }
    }
}

// ---------------- R0 fp32 VALU cell kernel (step 0 + ws fallback) ----------------
#define BT   64
#define JT   8
#define RT   32
#define KC   64
#define NT   256
#define NCHUNK 16
#define XSs  68
#define SMs  52
#define GBs  33

__global__ __launch_bounds__(NT) void lstm_cell_kernel(
    const float* __restrict__ Xbig0, const float* __restrict__ Wbig0,
    const float* __restrict__ Xbig1, const float* __restrict__ Wbig1,
    const float* __restrict__ Xsm0p, int K0,
    const float* __restrict__ Xsm1p, int K1,
    const float* __restrict__ Wsmall,
    const float* __restrict__ bih, const float* __restrict__ bhh,
    const float* __restrict__ cprev, float* __restrict__ cnew,
    const float* __restrict__ mask,
    float* __restrict__ hnew,
    const float* __restrict__ Wfc, const float* __restrict__ bfc,
    float* __restrict__ outp, int initOut)
{
    __shared__ float Xs[BT][XSs];
    __shared__ float Ws[RT][XSs];
    __shared__ float gbuf[BT][GBs];
    __shared__ float hbuf[BT][JT];
    __shared__ float Xsm[BT][SMs];
    __shared__ float Wsm[RT][SMs];

    const int tid = threadIdx.x;
    const int j0  = blockIdx.x * JT;
    const int b0  = blockIdx.y * BT;
    const int jp  = tid & 15;
    const int bq  = tid >> 4;

    auto GROW = [&](int r) { return ((r >> 3) * Hd + j0 + (r & 7)); };

    float acc[4][2];
    #pragma unroll
    for (int i = 0; i < 4; ++i) { acc[i][0] = 0.f; acc[i][1] = 0.f; }

    if (initOut && blockIdx.x == 0 && blockIdx.y == 0) {
        for (int i = tid; i < Bb * 3; i += NT) outp[i] = bfc[i % 3];
    }

    for (int seg = 0; seg < 2; ++seg) {
        const float* __restrict__ Xg = (seg == 0) ? Xbig0 : Xbig1;
        const float* __restrict__ Wg = (seg == 0) ? Wbig0 : Wbig1;
        if (Xg == nullptr) continue;

        float4 xr[4], wr[2];
        #pragma unroll
        for (int p = 0; p < 4; ++p) {
            int fi = p * NT + tid; int bloc = fi >> 4; int kq = fi & 15;
            xr[p] = *(const float4*)(Xg + (size_t)(b0 + bloc) * Hd + kq * 4);
        }
        #pragma unroll
        for (int p = 0; p < 2; ++p) {
            int fi = p * NT + tid; int r = fi >> 4; int kq = fi & 15;
            wr[p] = *(const float4*)(Wg + (size_t)GROW(r) * Hd + kq * 4);
        }
        #pragma unroll
        for (int p = 0; p < 4; ++p) { int fi = p * NT + tid; *(float4*)&Xs[fi >> 4][(fi & 15) * 4] = xr[p]; }
        #pragma unroll
        for (int p = 0; p < 2; ++p) { int fi = p * NT + tid; *(float4*)&Ws[fi >> 4][(fi & 15) * 4] = wr[p]; }
        __syncthreads();

        for (int kc = 0; kc < NCHUNK; ++kc) {
            const bool more = (kc + 1) < NCHUNK;
            if (more) {
                const int k0n = (kc + 1) * KC;
                #pragma unroll
                for (int p = 0; p < 4; ++p) {
                    int fi = p * NT + tid; int bloc = fi >> 4; int kq = fi & 15;
                    xr[p] = *(const float4*)(Xg + (size_t)(b0 + bloc) * Hd + k0n + kq * 4);
                }
                #pragma unroll
                for (int p = 0; p < 2; ++p) {
                    int fi = p * NT + tid; int r = fi >> 4; int kq = fi & 15;
                    wr[p] = *(const float4*)(Wg + (size_t)GROW(r) * Hd + k0n + kq * 4);
                }
            }
            #pragma unroll 4
            for (int kk = 0; kk < KC; kk += 4) {
                float4 w0 = *(const float4*)&Ws[jp][kk];
                float4 w1 = *(const float4*)&Ws[jp + 16][kk];
                #pragma unroll
                for (int bb = 0; bb < 4; ++bb) {
                    float4 xvv = *(const float4*)&Xs[bq + 16 * bb][kk];
                    acc[bb][0] += xvv.x * w0.x + xvv.y * w0.y + xvv.z * w0.z + xvv.w * w0.w;
                    acc[bb][1] += xvv.x * w1.x + xvv.y * w1.y + xvv.z * w1.z + xvv.w * w1.w;
                }
            }
            __syncthreads();
            if (more) {
                #pragma unroll
                for (int p = 0; p < 4; ++p) { int fi = p * NT + tid; *(float4*)&Xs[fi >> 4][(fi & 15) * 4] = xr[p]; }
                #pragma unroll
                for (int p = 0; p < 2; ++p) { int fi = p * NT + tid; *(float4*)&Ws[fi >> 4][(fi & 15) * 4] = wr[p]; }
                __syncthreads();
            }
        }
    }

    if (Wsmall) {
        const int Kt = K0 + K1;
        for (int i = tid; i < BT * Kt; i += NT) {
            int bloc = i / Kt, k = i % Kt;
            Xsm[bloc][k] = (k < K0) ? Xsm0p[(size_t)(b0 + bloc) * K0 + k]
                                    : Xsm1p[(size_t)(b0 + bloc) * K1 + (k - K0)];
        }
        for (int i = tid; i < RT * Kt; i += NT) {
            int r = i / Kt, k = i % Kt;
            Wsm[r][k] = Wsmall[(size_t)GROW(r) * Kt + k];
        }
        __syncthreads();
        for (int k = 0; k < Kt; ++k) {
            float w0 = Wsm[jp][k], w1 = Wsm[jp + 16][k];
            #pragma unroll
            for (int bb = 0; bb < 4; ++bb) {
                float xvv = Xsm[bq + 16 * bb][k];
                acc[bb][0] += xvv * w0;
                acc[bb][1] += xvv * w1;
            }
        }
    }

    __syncthreads();
    #pragma unroll
    for (int bb = 0; bb < 4; ++bb) {
        gbuf[bq + 16 * bb][jp]      = acc[bb][0];
        gbuf[bq + 16 * bb][jp + 16] = acc[bb][1];
    }
    __syncthreads();

    for (int p = tid; p < BT * JT; p += NT) {
        int bloc = p & (BT - 1);
        int j    = p >> 6;
        int bg   = b0 + bloc;
        int jc   = j0 + j;
        float gi = gbuf[bloc][j]      + bih[jc]          + bhh[jc];
        float gf = gbuf[bloc][8 + j]  + bih[Hd + jc]     + bhh[Hd + jc];
        float gg = gbuf[bloc][16 + j] + bih[2 * Hd + jc] + bhh[2 * Hd + jc];
        float go = gbuf[bloc][24 + j] + bih[3 * Hd + jc] + bhh[3 * Hd + jc];
        float cp = cprev[(size_t)bg * Hd + jc];
        float cn = sigm(gf) * cp + sigm(gi) * tanhf(gg);
        float hv = sigm(go) * tanhf(cn);
        if (mask) hv *= mask[(size_t)bg * Hd + jc];
        cnew[(size_t)bg * Hd + jc] = cn;
        hnew[(size_t)bg * Hd + jc] = hv;
        hbuf[bloc][j] = hv;
    }

    if (Wfc) {
        __syncthreads();
        if (tid < BT) {
            int bg = b0 + tid;
            #pragma unroll
            for (int m = 0; m < 3; ++m) {
                float s = 0.f;
                #pragma unroll
                for (int j = 0; j < JT; ++j) s += hbuf[tid][j] * Wfc[m * Hd + j0 + j];
                atomicAdd(&outp[bg * 3 + m], s);
            }
        }
    }
}

// ---------------- launch ----------------
extern "C" void kernel_launch(void* const* d_in, const int* in_sizes, int n_in,
                              void* d_out, int out_size, void* d_ws, size_t ws_size,
                              hipStream_t stream)
{
    (void)in_sizes; (void)n_in; (void)out_size;
    const float* cond   = (const float*)d_in[0];
    const float* noise  = (const float*)d_in[1];
    const float* h_init = (const float*)d_in[2];
    const float* c_init = (const float*)d_in[3];
    const float* dmask  = (const float*)d_in[4];
    const float* Wih0   = (const float*)d_in[5];
    const float* Whh0   = (const float*)d_in[6];
    const float* bih0   = (const float*)d_in[7];
    const float* bhh0   = (const float*)d_in[8];
    const float* Wih1   = (const float*)d_in[9];
    const float* Whh1   = (const float*)d_in[10];
    const float* bih1   = (const float*)d_in[11];
    const float* bhh1   = (const float*)d_in[12];
    const float* Wih2   = (const float*)d_in[13];
    const float* Whh2   = (const float*)d_in[14];
    const float* bih2   = (const float*)d_in[15];
    const float* bhh2   = (const float*)d_in[16];
    const float* Wfc    = (const float*)d_in[17];
    const float* bfc    = (const float*)d_in[18];
    float* out = (float*)d_out;

    char* wsb = (char*)d_ws;
    size_t off = 0;
    auto alloc = [&](size_t bytes) { size_t o = off; off += (bytes + 255) & ~(size_t)255; return o; };

    const size_t HB = (size_t)Bb * Hd * 2;   // bf16 h buffer
    const size_t HF = (size_t)Bb * Hd * 4;   // fp32

    size_t o_h1h[2] = { alloc(HB), alloc(HB) };
    size_t o_h1l[2] = { alloc(HB), alloc(HB) };
    size_t o_h2h[2] = { alloc(HB), alloc(HB) };
    size_t o_h2l[2] = { alloc(HB), alloc(HB) };
    size_t o_c1 = alloc(HF), o_c2 = alloc(HF);
    size_t o_f1 = alloc(HF), o_f2 = alloc(HF);
    size_t o_wfh = alloc((size_t)16 * Hd * 2);
    size_t o_wfl = alloc((size_t)16 * Hd * 2);
    size_t o_bar = alloc(BARWORDS * sizeof(unsigned));
    const size_t needed = off;

    if (ws_size < needed) {
        // -------- fallback: full R0 fp32 path --------
        float* ws = (float*)d_ws;
        const size_t S = (size_t)Bb * Hd;
        float* h1a = ws;         float* h1b = ws + S;
        float* h2a = ws + 2 * S; float* h2b = ws + 3 * S;
        float* c1  = ws + 4 * S; float* c2  = ws + 5 * S;
        dim3 grid(Hd / JT, Bb / BT);
        dim3 blk(NT);
        lstm_cell_kernel<<<grid, blk, 0, stream>>>(
            h_init, Whh0, nullptr, nullptr, cond, Cd, noise, Nd, Wih0,
            bih0, bhh0, c_init, c1, dmask, h1a, nullptr, bfc, out, 1);
        lstm_cell_kernel<<<grid, blk, 0, stream>>>(
            h1a, Wih2, h_init, Whh2, nullptr, 0, nullptr, 0, nullptr,
            bih2, bhh2, c_init, c2, nullptr, h2a, Wfc, bfc, out, 0);
        const float* h1prev = h1a; const float* h2prev = h2a;
        for (int t = 1; t < Ld; ++t) {
            float* h1cur = (t & 1) ? h1b : h1a;
            float* h2cur = (t & 1) ? h2b : h2a;
            lstm_cell_kernel<<<grid, blk, 0, stream>>>(
                h1prev, Whh1, nullptr, nullptr,
                cond + (size_t)t * Bb * Cd, Cd, out + (size_t)(t - 1) * Bb * Md, Md, Wih1,
                bih1, bhh1, c1, c1, dmask + (size_t)t * Bb * Hd, h1cur,
                nullptr, bfc, out + (size_t)t * Bb * Md, 1);
            lstm_cell_kernel<<<grid, blk, 0, stream>>>(
                h1cur, Wih2, h2prev, Whh2, nullptr, 0, nullptr, 0, nullptr,
                bih2, bhh2, c2, c2, nullptr, h2cur, Wfc, bfc, out + (size_t)t * Bb * Md, 0);
            h1prev = h1cur; h2prev = h2cur;
        }
        return;
    }

    auto U16 = [&](size_t o) { return (unsigned short*)(wsb + o); };
    auto F32 = [&](size_t o) { return (float*)(wsb + o); };
    unsigned* bar = (unsigned*)(wsb + o_bar);

    // preamble: barrier reset (every launch!) + padded bf16 Wfc
    init_bar_kernel<<<4, 256, 0, stream>>>(bar);
    prep_wfc<<<64, 256, 0, stream>>>(Wfc, U16(o_wfh), U16(o_wfl));

    // step 0 via the proven fp32 kernel (writes out[0], c1, c2, h1, h2)
    {
        dim3 grid(Hd / JT, Bb / BT);
        dim3 blk(NT);
        lstm_cell_kernel<<<grid, blk, 0, stream>>>(
            h_init, Whh0, nullptr, nullptr, cond, Cd, noise, Nd, Wih0,
            bih0, bhh0, c_init, F32(o_c1), dmask, F32(o_f1), nullptr, bfc, out, 1);
        lstm_cell_kernel<<<grid, blk, 0, stream>>>(
            F32(o_f1), Wih2, h_init, Whh2, nullptr, 0, nullptr, 0, nullptr,
            bih2, bhh2, c_init, F32(o_c2), nullptr, F32(o_f2), Wfc, bfc, out, 0);
        split_kg<<<512, 256, 0, stream>>>(F32(o_f1), U16(o_h1h[0]), U16(o_h1l[0]));
        split_kg<<<512, 256, 0, stream>>>(F32(o_f2), U16(o_h2h[0]), U16(o_h2l[0]));
    }

    // steps 1..255 in one persistent kernel
    lstm_seq<<<NWG, NTHR, 0, stream>>>(
        cond, dmask, Wih1, Whh1, bih1, bhh1, Wih2, Whh2, bih2, bhh2,
        bfc, F32(o_c1), F32(o_c2), U16(o_wfh), U16(o_wfl),
        U16(o_h1h[0]), U16(o_h1l[0]), U16(o_h1h[1]), U16(o_h1l[1]),
        U16(o_h2h[0]), U16(o_h2l[0]), U16(o_h2h[1]), U16(o_h2l[1]),
        out, bar);
}

// Round 4
// 9228.944 us; speedup vs baseline: 2.9692x; 1.0006x over previous
//
#include <hip/hip_runtime.h>
#include <math.h>

// ---------------- problem constants ----------------
#define Bb   128
#define Hd   1024
#define Ld   256
#define Cd   20
#define Nd   30
#define Md   3

#define NWG  256     // one workgroup per CU
#define NTHR 512     // 8 waves

// barrier region word offsets (unsigned words, 64B-strided slots) — R2-proven
#define CW    16
#define XCNT0 0            // 8 slots
#define CCNT  (8*CW)
#define CGEN  (9*CW)
#define XARR1 (10*CW)      // 8 slots
#define GC1   (18*CW)
#define GEN1  (19*CW)
#define XD1   (20*CW)      // 8 slots
#define XARR2 (28*CW)
#define GC2   (36*CW)
#define GEN2  (37*CW)
#define XD2   (38*CW)      // 8 slots
#define BARWORDS 1024

using bfrag = __attribute__((ext_vector_type(8)))  short;  // 8 bf16
using f32x4 = __attribute__((ext_vector_type(4)))  float;  // 16x16 C/D

union Pack8 { bfrag v; unsigned short u[8]; };

__device__ __forceinline__ float sigm(float x) { return 1.0f / (1.0f + expf(-x)); }

__device__ __forceinline__ unsigned short bf_rne(float x) {
    unsigned u = __float_as_uint(x);
    unsigned r = (u + 0x7fffu + ((u >> 16) & 1u)) >> 16;
    return (unsigned short)r;
}
__device__ __forceinline__ float bf_f(unsigned short h) {
    return __uint_as_float(((unsigned)h) << 16);
}

#define MFMA16(a,b,c) __builtin_amdgcn_mfma_f32_16x16x32_bf16((a),(b),(c),0,0,0)

__global__ void init_bar_kernel(unsigned* bar) {
    int i = blockIdx.x * blockDim.x + threadIdx.x;
    if (i < BARWORDS) bar[i] = 0u;
}

// fp32 h -> bf16 hi/lo in k-grouped layout [k/8][b][8]
__global__ void split_kg(const float* __restrict__ src,
                         unsigned short* __restrict__ hi,
                         unsigned short* __restrict__ lo)
{
    int i = blockIdx.x * blockDim.x + threadIdx.x;
    if (i >= Bb * Hd) return;
    int b = i >> 10, k = i & 1023;
    float x = src[i];
    unsigned short h = bf_rne(x);
    int d = ((k >> 3) * Bb + b) * 8 + (k & 7);
    hi[d] = h;
    lo[d] = bf_rne(x - bf_f(h));
}

// seed FC accumulator (3 parities): oacc[0] = out[0] - bfc ; oacc[1]=oacc[2]=0
__global__ void copy_out0(const float* __restrict__ o0,
                          const float* __restrict__ bfcp,
                          float* __restrict__ oacc)
{
    int i = threadIdx.x + blockIdx.x * blockDim.x;
    if (i < Bb * Md) {
        oacc[i] = o0[i] - bfcp[i % Md];
        oacc[Bb * Md + i] = 0.0f;
        oacc[2 * Bb * Md + i] = 0.0f;
    }
}

// ---------------- persistent fused sequence kernel ----------------
// 256 WGs x 512 thr (one per CU). Each WG owns 4 j-columns of both cells;
// Whh1/Wih2/Whh2 slices LDS-resident (96 KB). c1/c2 in registers.
// Per step: 2 fused A-passes (h2prev@Whh2 ; h1cur@{Wih2,Whh1-next}),
// FC via f32 VALU + device atomics (mod-3 rotated accumulator),
// 2 hierarchical grid barriers (R2-proven agent-scope variant).
__global__ __launch_bounds__(NTHR, 1) void lstm_seq(
    const float* __restrict__ cond, const float* __restrict__ dmask,
    const float* __restrict__ Wih1f, const float* __restrict__ Whh1f,
    const float* __restrict__ bih1, const float* __restrict__ bhh1,
    const float* __restrict__ Wih2f, const float* __restrict__ Whh2f,
    const float* __restrict__ bih2, const float* __restrict__ bhh2,
    const float* __restrict__ bfcp, const float* __restrict__ Wfc,
    const float* __restrict__ c1f, const float* __restrict__ c2f,
    unsigned short* __restrict__ h1h0, unsigned short* __restrict__ h1l0,
    unsigned short* __restrict__ h1h1, unsigned short* __restrict__ h1l1,
    unsigned short* __restrict__ h2h0, unsigned short* __restrict__ h2l0,
    unsigned short* __restrict__ h2h1, unsigned short* __restrict__ h2l1,
    float* __restrict__ oacc, float* __restrict__ outp, unsigned* bar)
{
    __shared__ unsigned short Wl1[16][1024];   // Whh1 slice
    __shared__ unsigned short Wl2[16][1024];   // Wih2 slice
    __shared__ unsigned short Wl3[16][1024];   // Whh2 slice
    __shared__ unsigned short Wsm[16][48];     // Wih1 slice (K=23 pad, 16B rows)
    __shared__ float gates[128][17];
    __shared__ float biasS1[16], biasS2[16];

    const int tid  = threadIdx.x;
    const int wave = tid >> 6;
    const int lane = tid & 63;
    const int lm = lane & 15;          // A-row (b) / B-col (n) within tile
    const int lq = lane >> 4;          // k-chunk (8 bf16)
    const int eb = tid >> 2;           // elementwise batch row
    const int ejj = tid & 3;           // elementwise j within slice
    const int bid = blockIdx.x;
    const int slice = (bid >> 3) + ((bid & 7) << 5);
    const int j0 = slice * 4;
    const int rot = (bid >> 3) & 31;   // per-CU k-rotation (de-lockstep L2)
    const int row = 16 * wave + lm;

    unsigned xreg;
    asm volatile("s_getreg_b32 %0, hwreg(HW_REG_XCC_ID)" : "=s"(xreg));
    const int xcd = (int)(xreg & 7u);

    // ---- one-time: weight slices -> LDS (bf16, k8-block XOR swizzle) ----
    for (int idx = tid; idx < 16 * 1024; idx += NTHR) {
        const int n = idx >> 10, k = idx & 1023;
        const size_t gr = (size_t)((n >> 2) * Hd + j0 + (n & 3)) * Hd + k;
        const int kp = (((k >> 3) ^ (n & 7)) << 3) | (k & 7);
        Wl1[n][kp] = bf_rne(Whh1f[gr]);
        Wl2[n][kp] = bf_rne(Wih2f[gr]);
        Wl3[n][kp] = bf_rne(Whh2f[gr]);
    }
    for (int idx = tid; idx < 16 * 48; idx += NTHR) {
        const int n = idx / 48, k = idx - n * 48;
        const int gr = (n >> 2) * Hd + j0 + (n & 3);
        Wsm[n][k] = (k < Cd + Md) ? bf_rne(Wih1f[(size_t)gr * (Cd + Md) + k]) : (unsigned short)0;
    }
    if (tid < 16) {
        const int gr = (tid >> 2) * Hd + j0 + (tid & 3);
        biasS1[tid] = bih1[gr] + bhh1[gr];
        biasS2[tid] = bih2[gr] + bhh2[gr];
    }

    // ---- census: expected WGs per XCD (once; agent scope) ----
    unsigned expX = 0, nx = 0;
    if (tid == 0) {
        __hip_atomic_fetch_add(&bar[XCNT0 + xcd * CW], 1u, __ATOMIC_RELAXED, __HIP_MEMORY_SCOPE_AGENT);
        unsigned v = __hip_atomic_fetch_add(&bar[CCNT], 1u, __ATOMIC_ACQ_REL, __HIP_MEMORY_SCOPE_AGENT);
        if (v == (unsigned)(NWG - 1)) {
            __hip_atomic_store(&bar[CGEN], 1u, __ATOMIC_RELEASE, __HIP_MEMORY_SCOPE_AGENT);
        } else {
            while (__hip_atomic_load(&bar[CGEN], __ATOMIC_RELAXED, __HIP_MEMORY_SCOPE_AGENT) == 0u)
                __builtin_amdgcn_s_sleep(8);
            __builtin_amdgcn_fence(__ATOMIC_ACQUIRE, "agent");
        }
        expX = __hip_atomic_load(&bar[XCNT0 + xcd * CW], __ATOMIC_RELAXED, __HIP_MEMORY_SCOPE_AGENT);
        for (int x = 0; x < 8; ++x)
            nx += (__hip_atomic_load(&bar[XCNT0 + x * CW], __ATOMIC_RELAXED, __HIP_MEMORY_SCOPE_AGENT) != 0u) ? 1u : 0u;
    }
    __syncthreads();   // also publishes LDS weight fill

    // ---- per-thread constants ----
    const unsigned eoffLin = (unsigned)eb * Hd + (unsigned)(j0 + ejj);
    const int jw = j0 + ejj;
    const unsigned idxKG = (unsigned)((jw >> 3) * Bb + eb) * 8u + (unsigned)(jw & 7);
    float c1 = c1f[eoffLin];
    float c2 = c2f[eoffLin];
    const float bfc0 = bfcp[0], bfc1 = bfcp[1], bfc2 = bfcp[2];
    const float wfcA = Wfc[0 * Hd + jw];
    const float wfcB = Wfc[1 * Hd + jw];
    const float wfcC = Wfc[2 * Hd + jw];
    const unsigned aoffB = (unsigned)(16 * wave + lm) * 16u + (unsigned)lq * 2048u;
    const char* w1p = (const char*)&Wl1[lm][0];
    const char* w2p = (const char*)&Wl2[lm][0];
    const char* w3p = (const char*)&Wl3[lm][0];
    const f32x4 z4 = {0.f, 0.f, 0.f, 0.f};

    // ---- barrier ops (R2-proven agent-scope hierarchical) ----
    auto b_arrive = [&](unsigned* XA, unsigned* GC, unsigned* GEN, unsigned t) -> bool {
        __syncthreads();                 // drains all waves' stores to L2
        bool am = false;
        if (tid == 0) {
            unsigned v = __hip_atomic_fetch_add(&XA[xcd * CW], 1u, __ATOMIC_RELAXED, __HIP_MEMORY_SCOPE_AGENT);
            if (v + 1u == expX * t) {    // last WG on this XCD for step t
                am = true;
                __builtin_amdgcn_fence(__ATOMIC_RELEASE, "agent");   // 1 wbl2/XCD
                unsigned w = __hip_atomic_fetch_add(GC, 1u, __ATOMIC_RELAXED, __HIP_MEMORY_SCOPE_AGENT);
                if (w + 1u == nx * t)
                    __hip_atomic_store(GEN, t, __ATOMIC_RELAXED, __HIP_MEMORY_SCOPE_AGENT);
            }
        }
        return am;
    };
    auto b_wait = [&](unsigned* GEN, unsigned* XD, unsigned t, bool am) {
        if (tid == 0) {
            if (am) {
                while (__hip_atomic_load(GEN, __ATOMIC_RELAXED, __HIP_MEMORY_SCOPE_AGENT) < t)
                    __builtin_amdgcn_s_sleep(2);
                __builtin_amdgcn_fence(__ATOMIC_ACQUIRE, "agent");   // 1 L2-inv/XCD
                asm volatile("s_waitcnt vmcnt(0) lgkmcnt(0)" ::: "memory");
                __hip_atomic_store(&XD[xcd * CW], t, __ATOMIC_RELAXED, __HIP_MEMORY_SCOPE_AGENT);
            } else {
                while (__hip_atomic_load(&XD[xcd * CW], __ATOMIC_RELAXED, __HIP_MEMORY_SCOPE_AGENT) < t)
                    __builtin_amdgcn_s_sleep(1);
            }
        }
        __syncthreads();
        asm volatile("buffer_inv sc0" ::: "memory");  // per-CU vL1 inv
    };

    // ---- GEMM helpers (A from global kg-layout, B from LDS swizzled) ----
    auto gemm_single = [&](const unsigned short* Hh, const unsigned short* Hl,
                           const char* wp, f32x4 acc) -> f32x4 {
        const char* ah = (const char*)Hh + aoffB;
        const char* al = (const char*)Hl + aoffB;
        #pragma unroll 4
        for (int i = 0; i < 32; ++i) {
            const int ks = (i + rot) & 31;
            bfrag xh = *(const bfrag*)(ah + ks * 8192);
            bfrag xl = *(const bfrag*)(al + ks * 8192);
            bfrag b  = *(const bfrag*)(wp + ((((ks * 4 + lq) ^ (lm & 7)) << 4)));
            acc = MFMA16(xh, b, acc);
            acc = MFMA16(xl, b, acc);
        }
        return acc;
    };
    auto gemm_dual = [&](const unsigned short* Hh, const unsigned short* Hl,
                         const char* wpA, f32x4& accA, const char* wpB, f32x4& accB) {
        const char* ah = (const char*)Hh + aoffB;
        const char* al = (const char*)Hl + aoffB;
        #pragma unroll 4
        for (int i = 0; i < 32; ++i) {
            const int ks = (i + rot) & 31;
            bfrag xh = *(const bfrag*)(ah + ks * 8192);
            bfrag xl = *(const bfrag*)(al + ks * 8192);
            const int bo = (((ks * 4 + lq) ^ (lm & 7)) << 4);
            bfrag ba = *(const bfrag*)(wpA + bo);
            bfrag bb = *(const bfrag*)(wpB + bo);
            accA = MFMA16(xh, ba, accA);
            accB = MFMA16(xh, bb, accB);
            accA = MFMA16(xl, ba, accA);
            accB = MFMA16(xl, bb, accB);
        }
    };
    auto putGates = [&](const f32x4& a) {
        #pragma unroll
        for (int r = 0; r < 4; ++r) gates[16 * wave + lq * 4 + r][lm] = a[r];
    };

    float cpre[8], cnext[8];
    auto prefetchCond = [&](int tn, float* cp) {
        const float* crow = cond + ((size_t)tn * Bb + row) * Cd;
        #pragma unroll
        for (int i = 0; i < 8; ++i) { int k = lq * 8 + i; cp[i] = (k < Cd) ? crow[k] : 0.f; }
    };

    // ---- prologue: t=1 inputs + acc1 = h1[0]@Whh1 ----
    prefetchCond(1, cpre);
    float mymask = dmask[(size_t)(Bb * Hd) + eoffLin];
    f32x4 acc1 = gemm_single(h1h0, h1l0, w1p, z4);
    bool last1 = false, last2 = false;

    unsigned* XA1 = bar + XARR1; unsigned* G1 = bar + GC1; unsigned* E1 = bar + GEN1; unsigned* D1 = bar + XD1;
    unsigned* XA2 = bar + XARR2; unsigned* G2 = bar + GC2; unsigned* E2 = bar + GEN2; unsigned* D2 = bar + XD2;

    for (int t = 1; t < Ld; ++t) {
        const int cur = t & 1;
        const unsigned short* A2h = cur ? h2h0 : h2h1;   // h2 prev
        const unsigned short* A2l = cur ? h2l0 : h2l1;
        unsigned short* O1h = cur ? h1h1 : h1h0;         // h1 cur
        unsigned short* O1l = cur ? h1l1 : h1l0;
        unsigned short* O2h = cur ? h2h1 : h2h0;         // h2 cur
        unsigned short* O2l = cur ? h2l1 : h2l0;
        // mod-3 FC accumulator rotation: read t-1, accumulate t, zero t+1
        float* oaccPrv = oacc + (size_t)((t + 2) % 3) * (Bb * Md);
        float* oaccCur = oacc + (size_t)(t % 3) * (Bb * Md);
        float* oaccNxt = oacc + (size_t)((t + 1) % 3) * (Bb * Md);

        // h2prev + FC atomics of t-1 visible after bar2(t-1)
        b_wait(E2, D2, (unsigned)(t - 1), last2);

        // out[t-1] rows for this thread's A-row (hidden under pass1)
        const float* orow = oaccPrv + row * 3;
        const float fr0 = orow[0] + bfc0;
        const float fr1 = orow[1] + bfc1;
        const float fr2 = orow[2] + bfc2;

        // ---- pass1: acc2 = h2prev @ Whh2 ----
        f32x4 acc2 = gemm_single(A2h, A2l, w3p, z4);

        // small segment: cat(cond[t], out[t-1]) @ Wih1^T (K=32 padded)
        {
            Pack8 ah, al;
            #pragma unroll
            for (int i = 0; i < 8; ++i) {
                const int k = lq * 8 + i;
                float x = cpre[i];
                if (k == Cd)     x = fr0;
                if (k == Cd + 1) x = fr1;
                if (k == Cd + 2) x = fr2;
                const unsigned short h = bf_rne(x);
                ah.u[i] = h;
                al.u[i] = bf_rne(x - bf_f(h));
            }
            const bfrag bs = *(const bfrag*)&Wsm[lm][lq * 8];
            acc1 = MFMA16(ah.v, bs, acc1);
            acc1 = MFMA16(al.v, bs, acc1);
        }

        // cell1 gates -> elementwise -> h1cur
        putGates(acc1);
        __syncthreads();
        {
            const float gi = gates[eb][ejj]      + biasS1[ejj];
            const float gf = gates[eb][4 + ejj]  + biasS1[4 + ejj];
            const float gg = gates[eb][8 + ejj]  + biasS1[8 + ejj];
            const float go = gates[eb][12 + ejj] + biasS1[12 + ejj];
            const float cn = sigm(gf) * c1 + sigm(gi) * tanhf(gg);
            c1 = cn;
            const float hv = sigm(go) * tanhf(cn) * mymask;
            const unsigned short hh = bf_rne(hv);
            O1h[idxKG] = hh;
            O1l[idxKG] = bf_rne(hv - bf_f(hh));
        }
        // WG0 publishes d_out[t-1]
        if (bid == 0 && lq == 0) {
            float* o = outp + (size_t)(t - 1) * (Bb * Md) + row * 3;
            o[0] = fr0; o[1] = fr1; o[2] = fr2;
        }

        last1 = b_arrive(XA1, G1, E1, (unsigned)t);
        // bar1 overlap: zero next-rotation FC accumulator (agent-scope stores)
        // + prefetch t+1 inputs. nxt != prv (mod 3) -> no read/zero race.
        if (bid < Bb && tid < Md)
            __hip_atomic_store(&oaccNxt[bid * 3 + tid], 0.0f, __ATOMIC_RELAXED, __HIP_MEMORY_SCOPE_AGENT);
        float mymask_next = 0.0f;
        if (t < Ld - 1) {
            prefetchCond(t + 1, cnext);
            mymask_next = dmask[(size_t)(t + 1) * (Bb * Hd) + eoffLin];
        }
        b_wait(E1, D1, (unsigned)t, last1);

        // ---- pass2 (fused): acc2 += h1cur@Wih2 ; acc1next = h1cur@Whh1 ----
        f32x4 acc1n = z4;
        gemm_dual(O1h, O1l, w2p, acc2, w1p, acc1n);

        // cell2 gates -> elementwise -> h2cur + FC partials
        putGates(acc2);
        __syncthreads();
        {
            const float gi = gates[eb][ejj]      + biasS2[ejj];
            const float gf = gates[eb][4 + ejj]  + biasS2[4 + ejj];
            const float gg = gates[eb][8 + ejj]  + biasS2[8 + ejj];
            const float go = gates[eb][12 + ejj] + biasS2[12 + ejj];
            const float cn = sigm(gf) * c2 + sigm(gi) * tanhf(gg);
            c2 = cn;
            const float hv = sigm(go) * tanhf(cn);
            const unsigned short hh = bf_rne(hv);
            O2h[idxKG] = hh;
            O2l[idxKG] = bf_rne(hv - bf_f(hh));
            // FC: out[t][eb][m] += sum over this WG's 4 j-cols
            float p0 = hv * wfcA, p1 = hv * wfcB, p2 = hv * wfcC;
            p0 += __shfl_xor(p0, 1); p0 += __shfl_xor(p0, 2);
            p1 += __shfl_xor(p1, 1); p1 += __shfl_xor(p1, 2);
            p2 += __shfl_xor(p2, 1); p2 += __shfl_xor(p2, 2);
            if (ejj == 0) {
                float* oc = oaccCur + eb * 3;
                atomicAdd(oc + 0, p0);
                atomicAdd(oc + 1, p1);
                atomicAdd(oc + 2, p2);
            }
        }

        last2 = b_arrive(XA2, G2, E2, (unsigned)t);
        acc1 = acc1n;
        mymask = mymask_next;
        #pragma unroll
        for (int i = 0; i < 8; ++i) cpre[i] = cnext[i];
    }

    // ---- epilogue: out[255] = oacc[(Ld-1)%3] + bfc (WG0 only) ----
    if (bid == 0) {
        if (tid == 0) {
            while (__hip_atomic_load(E2, __ATOMIC_RELAXED, __HIP_MEMORY_SCOPE_AGENT) < (unsigned)(Ld - 1))
                __builtin_amdgcn_s_sleep(2);
            __builtin_amdgcn_fence(__ATOMIC_ACQUIRE, "agent");
            asm volatile("s_waitcnt vmcnt(0) lgkmcnt(0)" ::: "memory");
        }
        __syncthreads();
        asm volatile("buffer_inv sc0" ::: "memory");
        const float* oa = oacc + (size_t)((Ld - 1) % 3) * (Bb * Md);
        if (tid < Bb) {
            float* o = outp + (size_t)(Ld - 1) * (Bb * Md) + tid * 3;
            o[0] = oa[tid * 3 + 0] + bfc0;
            o[1] = oa[tid * 3 + 1] + bfc1;
            o[2] = oa[tid * 3 + 2] + bfc2;
        }
    }
}

// ---------------- R0 fp32 VALU cell kernel (step 0 + ws fallback) ----------------
#define BT   64
#define JT   8
#define RT   32
#define KC   64
#define NT   256
#define NCHUNK 16
#define XSs  68
#define SMs  52
#define GBs  33

__global__ __launch_bounds__(NT) void lstm_cell_kernel(
    const float* __restrict__ Xbig0, const float* __restrict__ Wbig0,
    const float* __restrict__ Xbig1, const float* __restrict__ Wbig1,
    const float* __restrict__ Xsm0p, int K0,
    const float* __restrict__ Xsm1p, int K1,
    const float* __restrict__ Wsmall,
    const float* __restrict__ bih, const float* __restrict__ bhh,
    const float* __restrict__ cprev, float* __restrict__ cnew,
    const float* __restrict__ mask,
    float* __restrict__ hnew,
    const float* __restrict__ Wfc, const float* __restrict__ bfc,
    float* __restrict__ outp, int initOut)
{
    __shared__ float Xs[BT][XSs];
    __shared__ float Ws[RT][XSs];
    __shared__ float gbuf[BT][GBs];
    __shared__ float hbuf[BT][JT];
    __shared__ float Xsm[BT][SMs];
    __shared__ float Wsm[RT][SMs];

    const int tid = threadIdx.x;
    const int j0  = blockIdx.x * JT;
    const int b0  = blockIdx.y * BT;
    const int jp  = tid & 15;
    const int bq  = tid >> 4;

    auto GROW = [&](int r) { return ((r >> 3) * Hd + j0 + (r & 7)); };

    float acc[4][2];
    #pragma unroll
    for (int i = 0; i < 4; ++i) { acc[i][0] = 0.f; acc[i][1] = 0.f; }

    if (initOut && blockIdx.x == 0 && blockIdx.y == 0) {
        for (int i = tid; i < Bb * 3; i += NT) outp[i] = bfc[i % 3];
    }

    for (int seg = 0; seg < 2; ++seg) {
        const float* __restrict__ Xg = (seg == 0) ? Xbig0 : Xbig1;
        const float* __restrict__ Wg = (seg == 0) ? Wbig0 : Wbig1;
        if (Xg == nullptr) continue;

        float4 xr[4], wr[2];
        #pragma unroll
        for (int p = 0; p < 4; ++p) {
            int fi = p * NT + tid; int bloc = fi >> 4; int kq = fi & 15;
            xr[p] = *(const float4*)(Xg + (size_t)(b0 + bloc) * Hd + kq * 4);
        }
        #pragma unroll
        for (int p = 0; p < 2; ++p) {
            int fi = p * NT + tid; int r = fi >> 4; int kq = fi & 15;
            wr[p] = *(const float4*)(Wg + (size_t)GROW(r) * Hd + kq * 4);
        }
        #pragma unroll
        for (int p = 0; p < 4; ++p) { int fi = p * NT + tid; *(float4*)&Xs[fi >> 4][(fi & 15) * 4] = xr[p]; }
        #pragma unroll
        for (int p = 0; p < 2; ++p) { int fi = p * NT + tid; *(float4*)&Ws[fi >> 4][(fi & 15) * 4] = wr[p]; }
        __syncthreads();

        for (int kc = 0; kc < NCHUNK; ++kc) {
            const bool more = (kc + 1) < NCHUNK;
            if (more) {
                const int k0n = (kc + 1) * KC;
                #pragma unroll
                for (int p = 0; p < 4; ++p) {
                    int fi = p * NT + tid; int bloc = fi >> 4; int kq = fi & 15;
                    xr[p] = *(const float4*)(Xg + (size_t)(b0 + bloc) * Hd + k0n + kq * 4);
                }
                #pragma unroll
                for (int p = 0; p < 2; ++p) {
                    int fi = p * NT + tid; int r = fi >> 4; int kq = fi & 15;
                    wr[p] = *(const float4*)(Wg + (size_t)GROW(r) * Hd + k0n + kq * 4);
                }
            }
            #pragma unroll 4
            for (int kk = 0; kk < KC; kk += 4) {
                float4 w0 = *(const float4*)&Ws[jp][kk];
                float4 w1 = *(const float4*)&Ws[jp + 16][kk];
                #pragma unroll
                for (int bb = 0; bb < 4; ++bb) {
                    float4 xvv = *(const float4*)&Xs[bq + 16 * bb][kk];
                    acc[bb][0] += xvv.x * w0.x + xvv.y * w0.y + xvv.z * w0.z + xvv.w * w0.w;
                    acc[bb][1] += xvv.x * w1.x + xvv.y * w1.y + xvv.z * w1.z + xvv.w * w1.w;
                }
            }
            __syncthreads();
            if (more) {
                #pragma unroll
                for (int p = 0; p < 4; ++p) { int fi = p * NT + tid; *(float4*)&Xs[fi >> 4][(fi & 15) * 4] = xr[p]; }
                #pragma unroll
                for (int p = 0; p < 2; ++p) { int fi = p * NT + tid; *(float4*)&Ws[fi >> 4][(fi & 15) * 4] = wr[p]; }
                __syncthreads();
            }
        }
    }

    if (Wsmall) {
        const int Kt = K0 + K1;
        for (int i = tid; i < BT * Kt; i += NT) {
            int bloc = i / Kt, k = i % Kt;
            Xsm[bloc][k] = (k < K0) ? Xsm0p[(size_t)(b0 + bloc) * K0 + k]
                                    : Xsm1p[(size_t)(b0 + bloc) * K1 + (k - K0)];
        }
        for (int i = tid; i < RT * Kt; i += NT) {
            int r = i / Kt, k = i % Kt;
            Wsm[r][k] = Wsmall[(size_t)GROW(r) * Kt + k];
        }
        __syncthreads();
        for (int k = 0; k < Kt; ++k) {
            float w0 = Wsm[jp][k], w1 = Wsm[jp + 16][k];
            #pragma unroll
            for (int bb = 0; bb < 4; ++bb) {
                float xvv = Xsm[bq + 16 * bb][k];
                acc[bb][0] += xvv * w0;
                acc[bb][1] += xvv * w1;
            }
        }
    }

    __syncthreads();
    #pragma unroll
    for (int bb = 0; bb < 4; ++bb) {
        gbuf[bq + 16 * bb][jp]      = acc[bb][0];
        gbuf[bq + 16 * bb][jp + 16] = acc[bb][1];
    }
    __syncthreads();

    for (int p = tid; p < BT * JT; p += NT) {
        int bloc = p & (BT - 1);
        int j    = p >> 6;
        int bg   = b0 + bloc;
        int jc   = j0 + j;
        float gi = gbuf[bloc][j]      + bih[jc]          + bhh[jc];
        float gf = gbuf[bloc][8 + j]  + bih[Hd + jc]     + bhh[Hd + jc];
        float gg = gbuf[bloc][16 + j] + bih[2 * Hd + jc] + bhh[2 * Hd + jc];
        float go = gbuf[bloc][24 + j] + bih[3 * Hd + jc] + bhh[3 * Hd + jc];
        float cp = cprev[(size_t)bg * Hd + jc];
        float cn = sigm(gf) * cp + sigm(gi) * tanhf(gg);
        float hv = sigm(go) * tanhf(cn);
        if (mask) hv *= mask[(size_t)bg * Hd + jc];
        cnew[(size_t)bg * Hd + jc] = cn;
        hnew[(size_t)bg * Hd + jc] = hv;
        hbuf[bloc][j] = hv;
    }

    if (Wfc) {
        __syncthreads();
        if (tid < BT) {
            int bg = b0 + tid;
            #pragma unroll
            for (int m = 0; m < 3; ++m) {
                float s = 0.f;
                #pragma unroll
                for (int j = 0; j < JT; ++j) s += hbuf[tid][j] * Wfc[m * Hd + j0 + j];
                atomicAdd(&outp[bg * 3 + m], s);
            }
        }
    }
}

// ---------------- launch ----------------
extern "C" void kernel_launch(void* const* d_in, const int* in_sizes, int n_in,
                              void* d_out, int out_size, void* d_ws, size_t ws_size,
                              hipStream_t stream)
{
    (void)in_sizes; (void)n_in; (void)out_size;
    const float* cond   = (const float*)d_in[0];
    const float* noise  = (const float*)d_in[1];
    const float* h_init = (const float*)d_in[2];
    const float* c_init = (const float*)d_in[3];
    const float* dmask  = (const float*)d_in[4];
    const float* Wih0   = (const float*)d_in[5];
    const float* Whh0   = (const float*)d_in[6];
    const float* bih0   = (const float*)d_in[7];
    const float* bhh0   = (const float*)d_in[8];
    const float* Wih1   = (const float*)d_in[9];
    const float* Whh1   = (const float*)d_in[10];
    const float* bih1   = (const float*)d_in[11];
    const float* bhh1   = (const float*)d_in[12];
    const float* Wih2   = (const float*)d_in[13];
    const float* Whh2   = (const float*)d_in[14];
    const float* bih2   = (const float*)d_in[15];
    const float* bhh2   = (const float*)d_in[16];
    const float* Wfc    = (const float*)d_in[17];
    const float* bfc    = (const float*)d_in[18];
    float* out = (float*)d_out;

    char* wsb = (char*)d_ws;
    size_t off = 0;
    auto alloc = [&](size_t bytes) { size_t o = off; off += (bytes + 255) & ~(size_t)255; return o; };

    const size_t HB = (size_t)Bb * Hd * 2;   // bf16 h buffer
    const size_t HF = (size_t)Bb * Hd * 4;   // fp32

    size_t o_h1h[2] = { alloc(HB), alloc(HB) };
    size_t o_h1l[2] = { alloc(HB), alloc(HB) };
    size_t o_h2h[2] = { alloc(HB), alloc(HB) };
    size_t o_h2l[2] = { alloc(HB), alloc(HB) };
    size_t o_c1 = alloc(HF), o_c2 = alloc(HF);
    size_t o_f1 = alloc(HF), o_f2 = alloc(HF);
    size_t o_oacc = alloc((size_t)3 * Bb * Md * 4);
    size_t o_bar = alloc(BARWORDS * sizeof(unsigned));
    const size_t needed = off;

    if (ws_size < needed) {
        // -------- fallback: full R0 fp32 path --------
        float* ws = (float*)d_ws;
        const size_t S = (size_t)Bb * Hd;
        float* h1a = ws;         float* h1b = ws + S;
        float* h2a = ws + 2 * S; float* h2b = ws + 3 * S;
        float* c1  = ws + 4 * S; float* c2  = ws + 5 * S;
        dim3 grid(Hd / JT, Bb / BT);
        dim3 blk(NT);
        lstm_cell_kernel<<<grid, blk, 0, stream>>>(
            h_init, Whh0, nullptr, nullptr, cond, Cd, noise, Nd, Wih0,
            bih0, bhh0, c_init, c1, dmask, h1a, nullptr, bfc, out, 1);
        lstm_cell_kernel<<<grid, blk, 0, stream>>>(
            h1a, Wih2, h_init, Whh2, nullptr, 0, nullptr, 0, nullptr,
            bih2, bhh2, c_init, c2, nullptr, h2a, Wfc, bfc, out, 0);
        const float* h1prev = h1a; const float* h2prev = h2a;
        for (int t = 1; t < Ld; ++t) {
            float* h1cur = (t & 1) ? h1b : h1a;
            float* h2cur = (t & 1) ? h2b : h2a;
            lstm_cell_kernel<<<grid, blk, 0, stream>>>(
                h1prev, Whh1, nullptr, nullptr,
                cond + (size_t)t * Bb * Cd, Cd, out + (size_t)(t - 1) * Bb * Md, Md, Wih1,
                bih1, bhh1, c1, c1, dmask + (size_t)t * Bb * Hd, h1cur,
                nullptr, bfc, out + (size_t)t * Bb * Md, 1);
            lstm_cell_kernel<<<grid, blk, 0, stream>>>(
                h1cur, Wih2, h2prev, Whh2, nullptr, 0, nullptr, 0, nullptr,
                bih2, bhh2, c2, c2, nullptr, h2cur, Wfc, bfc, out + (size_t)t * Bb * Md, 0);
            h1prev = h1cur; h2prev = h2cur;
        }
        return;
    }

    auto U16 = [&](size_t o) { return (unsigned short*)(wsb + o); };
    auto F32 = [&](size_t o) { return (float*)(wsb + o); };
    unsigned* bar = (unsigned*)(wsb + o_bar);

    // preamble: barrier reset (every launch!)
    init_bar_kernel<<<4, 256, 0, stream>>>(bar);

    // step 0 via the proven fp32 kernel (writes out[0], c1, c2, h1, h2)
    {
        dim3 grid(Hd / JT, Bb / BT);
        dim3 blk(NT);
        lstm_cell_kernel<<<grid, blk, 0, stream>>>(
            h_init, Whh0, nullptr, nullptr, cond, Cd, noise, Nd, Wih0,
            bih0, bhh0, c_init, F32(o_c1), dmask, F32(o_f1), nullptr, bfc, out, 1);
        lstm_cell_kernel<<<grid, blk, 0, stream>>>(
            F32(o_f1), Wih2, h_init, Whh2, nullptr, 0, nullptr, 0, nullptr,
            bih2, bhh2, c_init, F32(o_c2), nullptr, F32(o_f2), Wfc, bfc, out, 0);
        split_kg<<<512, 256, 0, stream>>>(F32(o_f1), U16(o_h1h[0]), U16(o_h1l[0]));
        split_kg<<<512, 256, 0, stream>>>(F32(o_f2), U16(o_h2h[0]), U16(o_h2l[0]));
        copy_out0<<<2, 256, 0, stream>>>(out, bfc, F32(o_oacc));
    }

    // steps 1..255 in one persistent kernel
    lstm_seq<<<NWG, NTHR, 0, stream>>>(
        cond, dmask, Wih1, Whh1, bih1, bhh1, Wih2, Whh2, bih2, bhh2,
        bfc, Wfc, F32(o_c1), F32(o_c2),
        U16(o_h1h[0]), U16(o_h1l[0]), U16(o_h1h[1]), U16(o_h1l[1]),
        U16(o_h2h[0]), U16(o_h2l[0]), U16(o_h2h[1]), U16(o_h2l[1]),
        F32(o_oacc), out, bar);
}

// Round 6
// 9064.400 us; speedup vs baseline: 3.0231x; 1.0182x over previous
//
#include <hip/hip_runtime.h>
#include <math.h>

// ---------------- problem constants ----------------
#define Bb   128
#define Hd   1024
#define Ld   256
#define Cd   20
#define Nd   30
#define Md   3

#define NWG  256     // one workgroup per CU
#define NTHR 512     // 8 waves

// barrier region word offsets (unsigned words, 64B-strided slots).
// Timestamp-slot design: every word is REWRITTEN each step (monotone t),
// so a cache-inv that discards a line is self-healing. All accesses via
// __hip_atomic_* AGENT scope (the R2/R4-proven primitive set).
#define A1OFF   0                        // arrive slots bar1: (xcd*128+lidx)*16
#define A2OFF   16384                    // arrive slots bar2
#define R1OFF   32768                    // repArr bar1: xcd*16
#define R2OFF   (32768 + 128)
#define XD1OFF  (32768 + 256)            // per-XCD relay bar1
#define XD2OFF  (32768 + 384)
#define CXCNT   (32768 + 512)            // census: per-XCD WG count, xcd*16
#define CCCNT   (32768 + 640)
#define CCGEN   (32768 + 656)
#define BARWORDS 33536

using bfrag = __attribute__((ext_vector_type(8)))  short;  // 8 bf16
using f32x4 = __attribute__((ext_vector_type(4)))  float;  // 16x16 C/D

union Pack8 { bfrag v; unsigned short u[8]; };

__device__ __forceinline__ float sigm(float x) { return 1.0f / (1.0f + expf(-x)); }

__device__ __forceinline__ unsigned short bf_rne(float x) {
    unsigned u = __float_as_uint(x);
    unsigned r = (u + 0x7fffu + ((u >> 16) & 1u)) >> 16;
    return (unsigned short)r;
}
__device__ __forceinline__ float bf_f(unsigned short h) {
    return __uint_as_float(((unsigned)h) << 16);
}

#define MFMA16(a,b,c) __builtin_amdgcn_mfma_f32_16x16x32_bf16((a),(b),(c),0,0,0)

#define AG_LOAD(p)     __hip_atomic_load((p), __ATOMIC_RELAXED, __HIP_MEMORY_SCOPE_AGENT)
#define AG_STORE(p,v)  __hip_atomic_store((p), (v), __ATOMIC_RELAXED, __HIP_MEMORY_SCOPE_AGENT)

__global__ void init_bar_kernel(unsigned* bar) {
    int i = blockIdx.x * blockDim.x + threadIdx.x;
    if (i < BARWORDS) bar[i] = 0u;
}

// fp32 h -> bf16 hi/lo in k-grouped layout [k/8][b][8]
__global__ void split_kg(const float* __restrict__ src,
                         unsigned short* __restrict__ hi,
                         unsigned short* __restrict__ lo)
{
    int i = blockIdx.x * blockDim.x + threadIdx.x;
    if (i >= Bb * Hd) return;
    int b = i >> 10, k = i & 1023;
    float x = src[i];
    unsigned short h = bf_rne(x);
    int d = ((k >> 3) * Bb + b) * 8 + (k & 7);
    hi[d] = h;
    lo[d] = bf_rne(x - bf_f(h));
}

// seed FC accumulator (3 parities): oacc[0] = out[0] - bfc ; oacc[1]=oacc[2]=0
__global__ void copy_out0(const float* __restrict__ o0,
                          const float* __restrict__ bfcp,
                          float* __restrict__ oacc)
{
    int i = threadIdx.x + blockIdx.x * blockDim.x;
    if (i < Bb * Md) {
        oacc[i] = o0[i] - bfcp[i % Md];
        oacc[Bb * Md + i] = 0.0f;
        oacc[2 * Bb * Md + i] = 0.0f;
    }
}

// ---------------- persistent fused sequence kernel ----------------
// 256 WGs x 512 thr (one per CU). Each WG owns 4 j-columns of both cells;
// Whh1/Wih2/Whh2 slices LDS-resident (96 KB). c1/c2 in registers.
// Per step: 2 fused A-passes (h2prev@Whh2 ; h1cur@{Wih2,Whh1-next}),
// FC via f32 VALU + device atomics (mod-3 rotated accumulator),
// 2 hierarchical grid barriers: parallel timestamp-slot arrivals +
// wave-parallel polls (no serialized RMW chain); rep-only wbl2/inv fences.
__global__ __launch_bounds__(NTHR, 1) void lstm_seq(
    const float* __restrict__ cond, const float* __restrict__ dmask,
    const float* __restrict__ Wih1f, const float* __restrict__ Whh1f,
    const float* __restrict__ bih1, const float* __restrict__ bhh1,
    const float* __restrict__ Wih2f, const float* __restrict__ Whh2f,
    const float* __restrict__ bih2, const float* __restrict__ bhh2,
    const float* __restrict__ bfcp, const float* __restrict__ Wfc,
    const float* __restrict__ c1f, const float* __restrict__ c2f,
    unsigned short* __restrict__ h1h0, unsigned short* __restrict__ h1l0,
    unsigned short* __restrict__ h1h1, unsigned short* __restrict__ h1l1,
    unsigned short* __restrict__ h2h0, unsigned short* __restrict__ h2l0,
    unsigned short* __restrict__ h2h1, unsigned short* __restrict__ h2l1,
    float* __restrict__ oacc, float* __restrict__ outp, unsigned* bar)
{
    __shared__ unsigned short Wl1[16][1024];   // Whh1 slice
    __shared__ unsigned short Wl2[16][1024];   // Wih2 slice
    __shared__ unsigned short Wl3[16][1024];   // Whh2 slice
    __shared__ unsigned short Wsm[16][48];     // Wih1 slice (K=23 pad, 16B rows)
    __shared__ float gates[128][17];
    __shared__ float biasS1[16], biasS2[16];
    __shared__ unsigned shLidx, shExpX, shXmask;

    const int tid  = threadIdx.x;
    const int wave = tid >> 6;
    const int lane = tid & 63;
    const int lm = lane & 15;          // A-row (b) / B-col (n) within tile
    const int lq = lane >> 4;          // k-chunk (8 bf16)
    const int eb = tid >> 2;           // elementwise batch row
    const int ejj = tid & 3;           // elementwise j within slice
    const int bid = blockIdx.x;
    const int slice = (bid >> 3) + ((bid & 7) << 5);
    const int j0 = slice * 4;
    const int rot = (bid >> 3) & 31;   // per-CU k-rotation (de-lockstep L2)
    const int row = 16 * wave + lm;

    unsigned xreg;
    asm volatile("s_getreg_b32 %0, hwreg(HW_REG_XCC_ID)" : "=s"(xreg));
    const int xcd = (int)(xreg & 7u);

    // ---- one-time: weight slices -> LDS (bf16, k8-block XOR swizzle) ----
    for (int idx = tid; idx < 16 * 1024; idx += NTHR) {
        const int n = idx >> 10, k = idx & 1023;
        const size_t gr = (size_t)((n >> 2) * Hd + j0 + (n & 3)) * Hd + k;
        const int kp = (((k >> 3) ^ (n & 7)) << 3) | (k & 7);
        Wl1[n][kp] = bf_rne(Whh1f[gr]);
        Wl2[n][kp] = bf_rne(Wih2f[gr]);
        Wl3[n][kp] = bf_rne(Whh2f[gr]);
    }
    for (int idx = tid; idx < 16 * 48; idx += NTHR) {
        const int n = idx / 48, k = idx - n * 48;
        const int gr = (n >> 2) * Hd + j0 + (n & 3);
        Wsm[n][k] = (k < Cd + Md) ? bf_rne(Wih1f[(size_t)gr * (Cd + Md) + k]) : (unsigned short)0;
    }
    if (tid < 16) {
        const int gr = (tid >> 2) * Hd + j0 + (tid & 3);
        biasS1[tid] = bih1[gr] + bhh1[gr];
        biasS2[tid] = bih2[gr] + bhh2[gr];
    }

    // ---- census (once; R2/R4-proven agent-scope path). Yields local index. ----
    if (tid == 0) {
        unsigned li = __hip_atomic_fetch_add(&bar[CXCNT + xcd * 16], 1u, __ATOMIC_RELAXED, __HIP_MEMORY_SCOPE_AGENT);
        unsigned v  = __hip_atomic_fetch_add(&bar[CCCNT], 1u, __ATOMIC_ACQ_REL, __HIP_MEMORY_SCOPE_AGENT);
        if (v == (unsigned)(NWG - 1)) {
            __hip_atomic_store(&bar[CCGEN], 1u, __ATOMIC_RELEASE, __HIP_MEMORY_SCOPE_AGENT);
        } else {
            while (__hip_atomic_load(&bar[CCGEN], __ATOMIC_RELAXED, __HIP_MEMORY_SCOPE_AGENT) == 0u)
                __builtin_amdgcn_s_sleep(8);
            __builtin_amdgcn_fence(__ATOMIC_ACQUIRE, "agent");
        }
        unsigned xm = 0;
        for (int x = 0; x < 8; ++x)
            if (AG_LOAD(&bar[CXCNT + x * 16]) != 0u) xm |= (1u << x);
        shLidx  = li;
        shExpX  = AG_LOAD(&bar[CXCNT + xcd * 16]);
        shXmask = xm;
    }
    __syncthreads();   // also publishes LDS weight fill
    const unsigned lidx  = shLidx;
    const unsigned expX  = shExpX;
    const unsigned xmask = shXmask;
    const bool     isRep = (lidx == 0);

    // ---- per-thread constants ----
    const unsigned eoffLin = (unsigned)eb * Hd + (unsigned)(j0 + ejj);
    const int jw = j0 + ejj;
    const unsigned idxKG = (unsigned)((jw >> 3) * Bb + eb) * 8u + (unsigned)(jw & 7);
    float c1 = c1f[eoffLin];
    float c2 = c2f[eoffLin];
    const float bfc0 = bfcp[0], bfc1 = bfcp[1], bfc2 = bfcp[2];
    const float wfcA = Wfc[0 * Hd + jw];
    const float wfcB = Wfc[1 * Hd + jw];
    const float wfcC = Wfc[2 * Hd + jw];
    const unsigned aoffB = (unsigned)(16 * wave + lm) * 16u + (unsigned)lq * 2048u;
    const char* w1p = (const char*)&Wl1[lm][0];
    const char* w2p = (const char*)&Wl2[lm][0];
    const char* w3p = (const char*)&Wl3[lm][0];
    const f32x4 z4 = {0.f, 0.f, 0.f, 0.f};

    // ---- barrier ops: timestamp slots, O(1) depth, proven primitives ----
    auto b_arrive = [&](unsigned aoff, unsigned t) {
        __syncthreads();                 // drains all waves' stores into L2
        if (tid == 0)
            AG_STORE(&bar[aoff + ((unsigned)xcd * 128u + lidx) * 16u], t);
    };
    auto b_wait = [&](unsigned aoff, unsigned roff, unsigned xdoff, unsigned t) {
        if (isRep) {
            if (wave == 0) {
                // wave-parallel poll of this XCD's arrive slots
                const unsigned base = aoff + (unsigned)xcd * 128u * 16u;
                for (;;) {
                    int ok = 1;
                    for (unsigned s = (unsigned)lane; s < expX; s += 64u)
                        ok &= (AG_LOAD(&bar[base + s * 16u]) >= t) ? 1 : 0;
                    if (__all(ok)) break;
                    __builtin_amdgcn_s_sleep(1);
                }
                if (lane == 0) {
                    __builtin_amdgcn_fence(__ATOMIC_RELEASE, "agent");   // 1 wbl2/XCD
                    AG_STORE(&bar[roff + (unsigned)xcd * 16u], t);
                }
                // wave-parallel poll of all 8 repArr
                for (;;) {
                    unsigned v = (lane < 8 && ((xmask >> lane) & 1u))
                        ? AG_LOAD(&bar[roff + (unsigned)lane * 16u]) : t;
                    if (__all((int)(v >= t))) break;
                    __builtin_amdgcn_s_sleep(1);
                }
                if (lane == 0) {
                    __builtin_amdgcn_fence(__ATOMIC_ACQUIRE, "agent");   // 1 L2-inv/XCD
                    asm volatile("s_waitcnt vmcnt(0) lgkmcnt(0)" ::: "memory");
                    AG_STORE(&bar[xdoff + (unsigned)xcd * 16u], t);
                }
            }
        } else {
            if (tid == 0) {
                while (AG_LOAD(&bar[xdoff + (unsigned)xcd * 16u]) < t)
                    __builtin_amdgcn_s_sleep(1);
            }
        }
        __syncthreads();
        asm volatile("buffer_inv sc0" ::: "memory");  // per-CU vL1 inv
    };

    // ---- GEMM helpers (A from global kg-layout, B from LDS swizzled) ----
    auto gemm_single = [&](const unsigned short* Hh, const unsigned short* Hl,
                           const char* wp, f32x4 acc) -> f32x4 {
        const char* ah = (const char*)Hh + aoffB;
        const char* al = (const char*)Hl + aoffB;
        #pragma unroll 4
        for (int i = 0; i < 32; ++i) {
            const int ks = (i + rot) & 31;
            bfrag xh = *(const bfrag*)(ah + ks * 8192);
            bfrag xl = *(const bfrag*)(al + ks * 8192);
            bfrag b  = *(const bfrag*)(wp + ((((ks * 4 + lq) ^ (lm & 7)) << 4)));
            acc = MFMA16(xh, b, acc);
            acc = MFMA16(xl, b, acc);
        }
        return acc;
    };
    auto gemm_dual = [&](const unsigned short* Hh, const unsigned short* Hl,
                         const char* wpA, f32x4& accA, const char* wpB, f32x4& accB) {
        const char* ah = (const char*)Hh + aoffB;
        const char* al = (const char*)Hl + aoffB;
        #pragma unroll 4
        for (int i = 0; i < 32; ++i) {
            const int ks = (i + rot) & 31;
            bfrag xh = *(const bfrag*)(ah + ks * 8192);
            bfrag xl = *(const bfrag*)(al + ks * 8192);
            const int bo = (((ks * 4 + lq) ^ (lm & 7)) << 4);
            bfrag ba = *(const bfrag*)(wpA + bo);
            bfrag bb = *(const bfrag*)(wpB + bo);
            accA = MFMA16(xh, ba, accA);
            accB = MFMA16(xh, bb, accB);
            accA = MFMA16(xl, ba, accA);
            accB = MFMA16(xl, bb, accB);
        }
    };
    auto putGates = [&](const f32x4& a) {
        #pragma unroll
        for (int r = 0; r < 4; ++r) gates[16 * wave + lq * 4 + r][lm] = a[r];
    };

    float cpre[8], cnext[8];
    auto prefetchCond = [&](int tn, float* cp) {
        const float* crow = cond + ((size_t)tn * Bb + row) * Cd;
        #pragma unroll
        for (int i = 0; i < 8; ++i) { int k = lq * 8 + i; cp[i] = (k < Cd) ? crow[k] : 0.f; }
    };

    // ---- prologue: t=1 inputs + acc1 = h1[0]@Whh1 ----
    prefetchCond(1, cpre);
    float mymask = dmask[(size_t)(Bb * Hd) + eoffLin];
    f32x4 acc1 = gemm_single(h1h0, h1l0, w1p, z4);

    for (int t = 1; t < Ld; ++t) {
        const int cur = t & 1;
        const unsigned short* A2h = cur ? h2h0 : h2h1;   // h2 prev
        const unsigned short* A2l = cur ? h2l0 : h2l1;
        unsigned short* O1h = cur ? h1h1 : h1h0;         // h1 cur
        unsigned short* O1l = cur ? h1l1 : h1l0;
        unsigned short* O2h = cur ? h2h1 : h2h0;         // h2 cur
        unsigned short* O2l = cur ? h2l1 : h2l0;
        // mod-3 FC accumulator rotation: read t-1, accumulate t, zero t+1
        float* oaccPrv = oacc + (size_t)((t + 2) % 3) * (Bb * Md);
        float* oaccCur = oacc + (size_t)(t % 3) * (Bb * Md);
        float* oaccNxt = oacc + (size_t)((t + 1) % 3) * (Bb * Md);

        // h2prev + FC atomics of t-1 visible after bar2(t-1)
        b_wait(A2OFF, R2OFF, XD2OFF, (unsigned)(t - 1));

        // out[t-1] rows for this thread's A-row (hidden under pass1)
        const float* orow = oaccPrv + row * 3;
        const float fr0 = orow[0] + bfc0;
        const float fr1 = orow[1] + bfc1;
        const float fr2 = orow[2] + bfc2;

        // ---- pass1: acc2 = h2prev @ Whh2 ----
        f32x4 acc2 = gemm_single(A2h, A2l, w3p, z4);

        // small segment: cat(cond[t], out[t-1]) @ Wih1^T (K=32 padded)
        {
            Pack8 ah, al;
            #pragma unroll
            for (int i = 0; i < 8; ++i) {
                const int k = lq * 8 + i;
                float x = cpre[i];
                if (k == Cd)     x = fr0;
                if (k == Cd + 1) x = fr1;
                if (k == Cd + 2) x = fr2;
                const unsigned short h = bf_rne(x);
                ah.u[i] = h;
                al.u[i] = bf_rne(x - bf_f(h));
            }
            const bfrag bs = *(const bfrag*)&Wsm[lm][lq * 8];
            acc1 = MFMA16(ah.v, bs, acc1);
            acc1 = MFMA16(al.v, bs, acc1);
        }

        // cell1 gates -> elementwise -> h1cur
        putGates(acc1);
        __syncthreads();
        {
            const float gi = gates[eb][ejj]      + biasS1[ejj];
            const float gf = gates[eb][4 + ejj]  + biasS1[4 + ejj];
            const float gg = gates[eb][8 + ejj]  + biasS1[8 + ejj];
            const float go = gates[eb][12 + ejj] + biasS1[12 + ejj];
            const float cn = sigm(gf) * c1 + sigm(gi) * tanhf(gg);
            c1 = cn;
            const float hv = sigm(go) * tanhf(cn) * mymask;
            const unsigned short hh = bf_rne(hv);
            O1h[idxKG] = hh;
            O1l[idxKG] = bf_rne(hv - bf_f(hh));
        }
        // WG0 publishes d_out[t-1]
        if (bid == 0 && lq == 0) {
            float* o = outp + (size_t)(t - 1) * (Bb * Md) + row * 3;
            o[0] = fr0; o[1] = fr1; o[2] = fr2;
        }

        b_arrive(A1OFF, (unsigned)t);
        // bar1 shadow: zero next-rotation FC accumulator (agent stores,
        // nxt != prv mod 3 -> no race) + prefetch t+1 inputs
        if (bid < Bb && tid < Md)
            AG_STORE((unsigned*)&oaccNxt[bid * 3 + tid], 0u);
        float mymask_next = 0.0f;
        if (t < Ld - 1) {
            prefetchCond(t + 1, cnext);
            mymask_next = dmask[(size_t)(t + 1) * (Bb * Hd) + eoffLin];
        }
        b_wait(A1OFF, R1OFF, XD1OFF, (unsigned)t);

        // ---- pass2 (fused): acc2 += h1cur@Wih2 ; acc1next = h1cur@Whh1 ----
        f32x4 acc1n = z4;
        gemm_dual(O1h, O1l, w2p, acc2, w1p, acc1n);

        // cell2 gates -> elementwise -> h2cur + FC partials
        putGates(acc2);
        __syncthreads();
        {
            const float gi = gates[eb][ejj]      + biasS2[ejj];
            const float gf = gates[eb][4 + ejj]  + biasS2[4 + ejj];
            const float gg = gates[eb][8 + ejj]  + biasS2[8 + ejj];
            const float go = gates[eb][12 + ejj] + biasS2[12 + ejj];
            const float cn = sigm(gf) * c2 + sigm(gi) * tanhf(gg);
            c2 = cn;
            const float hv = sigm(go) * tanhf(cn);
            const unsigned short hh = bf_rne(hv);
            O2h[idxKG] = hh;
            O2l[idxKG] = bf_rne(hv - bf_f(hh));
            // FC: out[t][eb][m] += sum over this WG's 4 j-cols
            float p0 = hv * wfcA, p1 = hv * wfcB, p2 = hv * wfcC;
            p0 += __shfl_xor(p0, 1); p0 += __shfl_xor(p0, 2);
            p1 += __shfl_xor(p1, 1); p1 += __shfl_xor(p1, 2);
            p2 += __shfl_xor(p2, 1); p2 += __shfl_xor(p2, 2);
            if (ejj == 0) {
                float* oc = oaccCur + eb * 3;
                atomicAdd(oc + 0, p0);
                atomicAdd(oc + 1, p1);
                atomicAdd(oc + 2, p2);
            }
        }

        b_arrive(A2OFF, (unsigned)t);
        // bar2 shadow: next step's big GEMM (computed above as acc1n)
        acc1 = acc1n;
        mymask = mymask_next;
        #pragma unroll
        for (int i = 0; i < 8; ++i) cpre[i] = cnext[i];
    }

    // ---- epilogue: wait bar2(Ld-1) (reps relay), then WG0 writes out[255] ----
    b_wait(A2OFF, R2OFF, XD2OFF, (unsigned)(Ld - 1));
    if (bid == 0) {
        const float* oa = oacc + (size_t)((Ld - 1) % 3) * (Bb * Md);
        if (tid < Bb) {
            float* o = outp + (size_t)(Ld - 1) * (Bb * Md) + tid * 3;
            o[0] = oa[tid * 3 + 0] + bfc0;
            o[1] = oa[tid * 3 + 1] + bfc1;
            o[2] = oa[tid * 3 + 2] + bfc2;
        }
    }
}

// ---------------- R0 fp32 VALU cell kernel (step 0 + ws fallback) ----------------
#define BT   64
#define JT   8
#define RT   32
#define KC   64
#define NT   256
#define NCHUNK 16
#define XSs  68
#define SMs  52
#define GBs  33

__global__ __launch_bounds__(NT) void lstm_cell_kernel(
    const float* __restrict__ Xbig0, const float* __restrict__ Wbig0,
    const float* __restrict__ Xbig1, const float* __restrict__ Wbig1,
    const float* __restrict__ Xsm0p, int K0,
    const float* __restrict__ Xsm1p, int K1,
    const float* __restrict__ Wsmall,
    const float* __restrict__ bih, const float* __restrict__ bhh,
    const float* __restrict__ cprev, float* __restrict__ cnew,
    const float* __restrict__ mask,
    float* __restrict__ hnew,
    const float* __restrict__ Wfc, const float* __restrict__ bfc,
    float* __restrict__ outp, int initOut)
{
    __shared__ float Xs[BT][XSs];
    __shared__ float Ws[RT][XSs];
    __shared__ float gbuf[BT][GBs];
    __shared__ float hbuf[BT][JT];
    __shared__ float Xsm[BT][SMs];
    __shared__ float Wsm[RT][SMs];

    const int tid = threadIdx.x;
    const int j0  = blockIdx.x * JT;
    const int b0  = blockIdx.y * BT;
    const int jp  = tid & 15;
    const int bq  = tid >> 4;

    auto GROW = [&](int r) { return ((r >> 3) * Hd + j0 + (r & 7)); };

    float acc[4][2];
    #pragma unroll
    for (int i = 0; i < 4; ++i) { acc[i][0] = 0.f; acc[i][1] = 0.f; }

    if (initOut && blockIdx.x == 0 && blockIdx.y == 0) {
        for (int i = tid; i < Bb * 3; i += NT) outp[i] = bfc[i % 3];
    }

    for (int seg = 0; seg < 2; ++seg) {
        const float* __restrict__ Xg = (seg == 0) ? Xbig0 : Xbig1;
        const float* __restrict__ Wg = (seg == 0) ? Wbig0 : Wbig1;
        if (Xg == nullptr) continue;

        float4 xr[4], wr[2];
        #pragma unroll
        for (int p = 0; p < 4; ++p) {
            int fi = p * NT + tid; int bloc = fi >> 4; int kq = fi & 15;
            xr[p] = *(const float4*)(Xg + (size_t)(b0 + bloc) * Hd + kq * 4);
        }
        #pragma unroll
        for (int p = 0; p < 2; ++p) {
            int fi = p * NT + tid; int r = fi >> 4; int kq = fi & 15;
            wr[p] = *(const float4*)(Wg + (size_t)GROW(r) * Hd + kq * 4);
        }
        #pragma unroll
        for (int p = 0; p < 4; ++p) { int fi = p * NT + tid; *(float4*)&Xs[fi >> 4][(fi & 15) * 4] = xr[p]; }
        #pragma unroll
        for (int p = 0; p < 2; ++p) { int fi = p * NT + tid; *(float4*)&Ws[fi >> 4][(fi & 15) * 4] = wr[p]; }
        __syncthreads();

        for (int kc = 0; kc < NCHUNK; ++kc) {
            const bool more = (kc + 1) < NCHUNK;
            if (more) {
                const int k0n = (kc + 1) * KC;
                #pragma unroll
                for (int p = 0; p < 4; ++p) {
                    int fi = p * NT + tid; int bloc = fi >> 4; int kq = fi & 15;
                    xr[p] = *(const float4*)(Xg + (size_t)(b0 + bloc) * Hd + k0n + kq * 4);
                }
                #pragma unroll
                for (int p = 0; p < 2; ++p) {
                    int fi = p * NT + tid; int r = fi >> 4; int kq = fi & 15;
                    wr[p] = *(const float4*)(Wg + (size_t)GROW(r) * Hd + k0n + kq * 4);
                }
            }
            #pragma unroll 4
            for (int kk = 0; kk < KC; kk += 4) {
                float4 w0 = *(const float4*)&Ws[jp][kk];
                float4 w1 = *(const float4*)&Ws[jp + 16][kk];
                #pragma unroll
                for (int bb = 0; bb < 4; ++bb) {
                    float4 xvv = *(const float4*)&Xs[bq + 16 * bb][kk];
                    acc[bb][0] += xvv.x * w0.x + xvv.y * w0.y + xvv.z * w0.z + xvv.w * w0.w;
                    acc[bb][1] += xvv.x * w1.x + xvv.y * w1.y + xvv.z * w1.z + xvv.w * w1.w;
                }
            }
            __syncthreads();
            if (more) {
                #pragma unroll
                for (int p = 0; p < 4; ++p) { int fi = p * NT + tid; *(float4*)&Xs[fi >> 4][(fi & 15) * 4] = xr[p]; }
                #pragma unroll
                for (int p = 0; p < 2; ++p) { int fi = p * NT + tid; *(float4*)&Ws[fi >> 4][(fi & 15) * 4] = wr[p]; }
                __syncthreads();
            }
        }
    }

    if (Wsmall) {
        const int Kt = K0 + K1;
        for (int i = tid; i < BT * Kt; i += NT) {
            int bloc = i / Kt, k = i % Kt;
            Xsm[bloc][k] = (k < K0) ? Xsm0p[(size_t)(b0 + bloc) * K0 + k]
                                    : Xsm1p[(size_t)(b0 + bloc) * K1 + (k - K0)];
        }
        for (int i = tid; i < RT * Kt; i += NT) {
            int r = i / Kt, k = i % Kt;
            Wsm[r][k] = Wsmall[(size_t)GROW(r) * Kt + k];
        }
        __syncthreads();
        for (int k = 0; k < Kt; ++k) {
            float w0 = Wsm[jp][k], w1 = Wsm[jp + 16][k];
            #pragma unroll
            for (int bb = 0; bb < 4; ++bb) {
                float xvv = Xsm[bq + 16 * bb][k];
                acc[bb][0] += xvv * w0;
                acc[bb][1] += xvv * w1;
            }
        }
    }

    __syncthreads();
    #pragma unroll
    for (int bb = 0; bb < 4; ++bb) {
        gbuf[bq + 16 * bb][jp]      = acc[bb][0];
        gbuf[bq + 16 * bb][jp + 16] = acc[bb][1];
    }
    __syncthreads();

    for (int p = tid; p < BT * JT; p += NT) {
        int bloc = p & (BT - 1);
        int j    = p >> 6;
        int bg   = b0 + bloc;
        int jc   = j0 + j;
        float gi = gbuf[bloc][j]      + bih[jc]          + bhh[jc];
        float gf = gbuf[bloc][8 + j]  + bih[Hd + jc]     + bhh[Hd + jc];
        float gg = gbuf[bloc][16 + j] + bih[2 * Hd + jc] + bhh[2 * Hd + jc];
        float go = gbuf[bloc][24 + j] + bih[3 * Hd + jc] + bhh[3 * Hd + jc];
        float cp = cprev[(size_t)bg * Hd + jc];
        float cn = sigm(gf) * cp + sigm(gi) * tanhf(gg);
        float hv = sigm(go) * tanhf(cn);
        if (mask) hv *= mask[(size_t)bg * Hd + jc];
        cnew[(size_t)bg * Hd + jc] = cn;
        hnew[(size_t)bg * Hd + jc] = hv;
        hbuf[bloc][j] = hv;
    }

    if (Wfc) {
        __syncthreads();
        if (tid < BT) {
            int bg = b0 + tid;
            #pragma unroll
            for (int m = 0; m < 3; ++m) {
                float s = 0.f;
                #pragma unroll
                for (int j = 0; j < JT; ++j) s += hbuf[tid][j] * Wfc[m * Hd + j0 + j];
                atomicAdd(&outp[bg * 3 + m], s);
            }
        }
    }
}

// ---------------- launch ----------------
extern "C" void kernel_launch(void* const* d_in, const int* in_sizes, int n_in,
                              void* d_out, int out_size, void* d_ws, size_t ws_size,
                              hipStream_t stream)
{
    (void)in_sizes; (void)n_in; (void)out_size;
    const float* cond   = (const float*)d_in[0];
    const float* noise  = (const float*)d_in[1];
    const float* h_init = (const float*)d_in[2];
    const float* c_init = (const float*)d_in[3];
    const float* dmask  = (const float*)d_in[4];
    const float* Wih0   = (const float*)d_in[5];
    const float* Whh0   = (const float*)d_in[6];
    const float* bih0   = (const float*)d_in[7];
    const float* bhh0   = (const float*)d_in[8];
    const float* Wih1   = (const float*)d_in[9];
    const float* Whh1   = (const float*)d_in[10];
    const float* bih1   = (const float*)d_in[11];
    const float* bhh1   = (const float*)d_in[12];
    const float* Wih2   = (const float*)d_in[13];
    const float* Whh2   = (const float*)d_in[14];
    const float* bih2   = (const float*)d_in[15];
    const float* bhh2   = (const float*)d_in[16];
    const float* Wfc    = (const float*)d_in[17];
    const float* bfc    = (const float*)d_in[18];
    float* out = (float*)d_out;

    char* wsb = (char*)d_ws;
    size_t off = 0;
    auto alloc = [&](size_t bytes) { size_t o = off; off += (bytes + 255) & ~(size_t)255; return o; };

    const size_t HB = (size_t)Bb * Hd * 2;   // bf16 h buffer
    const size_t HF = (size_t)Bb * Hd * 4;   // fp32

    size_t o_h1h[2] = { alloc(HB), alloc(HB) };
    size_t o_h1l[2] = { alloc(HB), alloc(HB) };
    size_t o_h2h[2] = { alloc(HB), alloc(HB) };
    size_t o_h2l[2] = { alloc(HB), alloc(HB) };
    size_t o_c1 = alloc(HF), o_c2 = alloc(HF);
    size_t o_f1 = alloc(HF), o_f2 = alloc(HF);
    size_t o_oacc = alloc((size_t)3 * Bb * Md * 4);
    size_t o_bar = alloc(BARWORDS * sizeof(unsigned));
    const size_t needed = off;

    if (ws_size < needed) {
        // -------- fallback: full R0 fp32 path --------
        float* ws = (float*)d_ws;
        const size_t S = (size_t)Bb * Hd;
        float* h1a = ws;         float* h1b = ws + S;
        float* h2a = ws + 2 * S; float* h2b = ws + 3 * S;
        float* c1  = ws + 4 * S; float* c2  = ws + 5 * S;
        dim3 grid(Hd / JT, Bb / BT);
        dim3 blk(NT);
        lstm_cell_kernel<<<grid, blk, 0, stream>>>(
            h_init, Whh0, nullptr, nullptr, cond, Cd, noise, Nd, Wih0,
            bih0, bhh0, c_init, c1, dmask, h1a, nullptr, bfc, out, 1);
        lstm_cell_kernel<<<grid, blk, 0, stream>>>(
            h1a, Wih2, h_init, Whh2, nullptr, 0, nullptr, 0, nullptr,
            bih2, bhh2, c_init, c2, nullptr, h2a, Wfc, bfc, out, 0);
        const float* h1prev = h1a; const float* h2prev = h2a;
        for (int t = 1; t < Ld; ++t) {
            float* h1cur = (t & 1) ? h1b : h1a;
            float* h2cur = (t & 1) ? h2b : h2a;
            lstm_cell_kernel<<<grid, blk, 0, stream>>>(
                h1prev, Whh1, nullptr, nullptr,
                cond + (size_t)t * Bb * Cd, Cd, out + (size_t)(t - 1) * Bb * Md, Md, Wih1,
                bih1, bhh1, c1, c1, dmask + (size_t)t * Bb * Hd, h1cur,
                nullptr, bfc, out + (size_t)t * Bb * Md, 1);
            lstm_cell_kernel<<<grid, blk, 0, stream>>>(
                h1cur, Wih2, h2prev, Whh2, nullptr, 0, nullptr, 0, nullptr,
                bih2, bhh2, c2, c2, nullptr, h2cur, Wfc, bfc, out + (size_t)t * Bb * Md, 0);
            h1prev = h1cur; h2prev = h2cur;
        }
        return;
    }

    auto U16 = [&](size_t o) { return (unsigned short*)(wsb + o); };
    auto F32 = [&](size_t o) { return (float*)(wsb + o); };
    unsigned* bar = (unsigned*)(wsb + o_bar);

    // preamble: barrier reset (every launch!)
    init_bar_kernel<<<(BARWORDS + 255) / 256, 256, 0, stream>>>(bar);

    // step 0 via the proven fp32 kernel (writes out[0], c1, c2, h1, h2)
    {
        dim3 grid(Hd / JT, Bb / BT);
        dim3 blk(NT);
        lstm_cell_kernel<<<grid, blk, 0, stream>>>(
            h_init, Whh0, nullptr, nullptr, cond, Cd, noise, Nd, Wih0,
            bih0, bhh0, c_init, F32(o_c1), dmask, F32(o_f1), nullptr, bfc, out, 1);
        lstm_cell_kernel<<<grid, blk, 0, stream>>>(
            F32(o_f1), Wih2, h_init, Whh2, nullptr, 0, nullptr, 0, nullptr,
            bih2, bhh2, c_init, F32(o_c2), nullptr, F32(o_f2), Wfc, bfc, out, 0);
        split_kg<<<512, 256, 0, stream>>>(F32(o_f1), U16(o_h1h[0]), U16(o_h1l[0]));
        split_kg<<<512, 256, 0, stream>>>(F32(o_f2), U16(o_h2h[0]), U16(o_h2l[0]));
        copy_out0<<<2, 256, 0, stream>>>(out, bfc, F32(o_oacc));
    }

    // steps 1..255 in one persistent kernel
    lstm_seq<<<NWG, NTHR, 0, stream>>>(
        cond, dmask, Wih1, Whh1, bih1, bhh1, Wih2, Whh2, bih2, bhh2,
        bfc, Wfc, F32(o_c1), F32(o_c2),
        U16(o_h1h[0]), U16(o_h1l[0]), U16(o_h1h[1]), U16(o_h1l[1]),
        U16(o_h2h[0]), U16(o_h2l[0]), U16(o_h2h[1]), U16(o_h2l[1]),
        F32(o_oacc), out, bar);
}